// Round 1
// baseline (445.895 us; speedup 1.0000x reference)
//
#include <hip/hip_runtime.h>
#include <math.h>

#define NB 16
#define ND 256
#define NL 200
#define NT 1000

// ---- workspace layout (float offsets), total ~31.5 MiB ----
#define OFF_PHT   0u        // phT[b][l][d]          819200
#define OFF_G     819200u   // G[b*4+q][l][n]        3276800
#define OFF_VCWHC 4096000u  // vc then whc in-place  4096000
#define OFF_HW    8192000u  // hw[b][l][8]           25600
#define OFF_HC    8217600u  // hc[b][l][8]           25600
#define OFF_SK    8243200u  // exclusive cumsum      3200
#define OFF_EW    8246400u  // Ew[oc][k][d]          6144
#define OFF_EC    8252544u  //                       6144
#define OFF_BW2   8258688u  // bias per (oc,k)       24
#define OFF_BC2   8258712u  //                       24
#define OFF_FL    8258736u  // frame_lengths (int)   16

__device__ __forceinline__ float silu_f(float x){ return x / (1.f + expf(-x)); }

// ---------------- K1: durations -> sk, frame_lengths, frame_mask ----------------
__global__ __launch_bounds__(256) void k_prep(const float* __restrict__ dur,
    float* __restrict__ sk_ws, int* __restrict__ fl_ws,
    float* __restrict__ o_fm, float* __restrict__ o_fl)
{
  int b = blockIdx.x, tid = threadIdx.x;
  __shared__ float sdur[NL];
  __shared__ float ssk[NL];
  __shared__ int sfl;
  if (tid < NL) sdur[tid] = dur[b*NL + tid];
  __syncthreads();
  if (tid == 0){
    float run = 0.f;
    for (int l = 0; l < NL; ++l){ ssk[l] = run; run += sdur[l]; }
    int fl = (int)rintf(run);            // round-half-even, matches jnp.round
    fl = fl < 0 ? 0 : (fl > NT ? NT : fl);
    sfl = fl; fl_ws[b] = fl; o_fl[b] = (float)fl;
  }
  __syncthreads();
  if (tid < NL) sk_ws[b*NL + tid] = ssk[tid];
  for (int t = tid; t < NT; t += 256) o_fm[b*NT + t] = (t < sfl) ? 1.f : 0.f;
}

// ---------------- K2: fold pointwise Wp into conv: E[oc,k,d], bias2[oc,k] ------
__global__ __launch_bounds__(256) void k_combine(
    const float* __restrict__ Wp_w, const float* __restrict__ C_w, const float* __restrict__ bp_w,
    const float* __restrict__ Wp_c, const float* __restrict__ C_c, const float* __restrict__ bp_c,
    float* __restrict__ Ew, float* __restrict__ Ec,
    float* __restrict__ bw2, float* __restrict__ bc2)
{
  int gid = blockIdx.x*256 + threadIdx.x;   // 12288 = 2 * 8*3*256
  int branch = gid / 6144;
  int r = gid % 6144;
  int d = r & 255;
  int ock = r >> 8;            // oc*3+k
  int oc = ock / 3, k = ock % 3;
  const float* Wp = branch ? Wp_c : Wp_w;
  const float* C  = branch ? C_c  : C_w;
  float acc = 0.f;
  for (int i = 0; i < ND; ++i) acc += C[(oc*ND + i)*3 + k] * Wp[i*ND + d];
  (branch ? Ec : Ew)[r] = acc;
  if (d == 0){
    const float* bp = branch ? bp_c : bp_w;
    float bb = 0.f;
    for (int i = 0; i < ND; ++i) bb += C[(oc*ND + i)*3 + k] * bp[i];
    (branch ? bc2 : bw2)[ock] = bb;
  }
}

// ---------------- K3: phoneme (b,d,l) -> phT (b,l,d) ---------------------------
__global__ void k_transpose(const float* __restrict__ ph, float* __restrict__ phT)
{
  __shared__ float tile[32][33];
  int b = blockIdx.z;
  int l0 = blockIdx.x*32, d0 = blockIdx.y*32;
  int tx = threadIdx.x, ty = threadIdx.y;  // 32 x 8
  #pragma unroll
  for (int i = 0; i < 4; ++i){
    int d = d0 + ty + i*8, l = l0 + tx;
    tile[ty + i*8][tx] = (l < NL) ? ph[((size_t)b*ND + d)*NL + l] : 0.f;
  }
  __syncthreads();
  #pragma unroll
  for (int i = 0; i < 4; ++i){
    int l = l0 + ty + i*8, d = d0 + tx;
    if (l < NL) phT[((size_t)b*NL + l)*ND + d] = tile[tx][ty + i*8];
  }
}

// ---------------- K4: hw/hc = silu(conv(pointwise(ph))) * pm -------------------
__global__ __launch_bounds__(256) void k_hwc(const float* __restrict__ phT,
    const float* __restrict__ dur,
    const float* __restrict__ Ew, const float* __restrict__ Ec,
    const float* __restrict__ bw2, const float* __restrict__ bc2,
    const float* __restrict__ cbw, const float* __restrict__ cbc,
    float* __restrict__ hw, float* __restrict__ hc)
{
  int gid = blockIdx.x*256 + threadIdx.x;   // 51200 = 16*200*16
  int b = gid / (NL*16);
  int r = gid % (NL*16);
  int l = r >> 4;
  int u = r & 15;
  int branch = u >> 3, oc = u & 7;
  const float* E  = branch ? Ec  : Ew;
  const float* b2 = branch ? bc2 : bw2;
  float val = (branch ? cbc : cbw)[oc];
  #pragma unroll
  for (int k = 0; k < 3; ++k){
    int ll = l + k - 1;
    if (ll < 0 || ll >= NL) continue;      // SAME zero-padding: drop term+bias
    float acc = b2[oc*3 + k];
    const float* Erow = E + (oc*3 + k)*ND;
    const float* prow = phT + ((size_t)b*NL + ll)*ND;
    for (int d = 0; d < ND; ++d) acc += Erow[d] * prow[d];
    val += acc;
  }
  float pm = (dur[b*NL + l] > 0.5f) ? 1.f : 0.f;
  (branch ? hc : hw)[(b*NL + l)*8 + oc] = silu_f(val) * pm;
}

// ---------------- K5: per (b,t): MLPs, softmax over l, w out, vc ---------------
__global__ __launch_bounds__(256) void k_wsoft(
    const float* __restrict__ dur, const float* __restrict__ sk_ws,
    const int* __restrict__ fl_ws,
    const float* __restrict__ hw, const float* __restrict__ hc,
    const float* __restrict__ Mw, const float* __restrict__ mbw,
    const float* __restrict__ Mc, const float* __restrict__ mbc,
    const float* __restrict__ Lc, const float* __restrict__ lbc,
    float* __restrict__ wout, float* __restrict__ vcwhc)
{
  int bt = blockIdx.x;
  int b = bt / NT, t = bt - b*NT;
  int tid = threadIdx.x;
  int wave = tid >> 6, lane = tid & 63;
  bool fm = t < fl_ws[b];
  bool act = tid < NL;
  __shared__ float red[4][8];

  float z[4] = {0,0,0,0};
  float cv[2] = {0,0};
  float pmf = 0.f;
  if (act){
    float dl = dur[b*NL + tid];
    pmf = (dl > 0.5f) ? 1.f : 0.f;
    bool am = fm && (pmf > 0.f);
    float S  = am ? ((float)(t+1) - sk_ws[b*NL + tid]) : 0.f;
    float Ev = am ? dl : 0.f;
    const float* hwp = hw + (b*NL + tid)*8;
    #pragma unroll
    for (int q = 0; q < 4; ++q){
      float a = mbw[q] + S*Mw[q] + Ev*Mw[4 + q];
      #pragma unroll
      for (int j = 0; j < 8; ++j) a += hwp[j]*Mw[(2 + j)*4 + q];
      z[q] = silu_f(a);
    }
    const float* hcp = hc + (b*NL + tid)*8;
    #pragma unroll
    for (int p = 0; p < 2; ++p){
      float a = mbc[p] + S*Mc[p] + Ev*Mc[2 + p];
      #pragma unroll
      for (int j = 0; j < 8; ++j) a += hcp[j]*Mc[(2 + j)*2 + p];
      cv[p] = silu_f(a);
    }
  }
  bool valid = act && (pmf > 0.f);
  // ---- block max per q ----
  #pragma unroll
  for (int q = 0; q < 4; ++q){
    float v = valid ? z[q] : -INFINITY;
    #pragma unroll
    for (int off = 32; off > 0; off >>= 1) v = fmaxf(v, __shfl_down(v, off));
    if (lane == 0) red[wave][q] = v;
  }
  __syncthreads();
  float m4[4];
  #pragma unroll
  for (int q = 0; q < 4; ++q)
    m4[q] = fmaxf(fmaxf(red[0][q], red[1][q]), fmaxf(red[2][q], red[3][q]));
  __syncthreads();
  // ---- block sum of exp per q ----
  float ev[4];
  #pragma unroll
  for (int q = 0; q < 4; ++q){
    ev[q] = valid ? expf(z[q] - m4[q]) : 0.f;
    float v = ev[q];
    #pragma unroll
    for (int off = 32; off > 0; off >>= 1) v += __shfl_down(v, off);
    if (lane == 0) red[wave][q] = v;
  }
  __syncthreads();
  float s4[4];
  #pragma unroll
  for (int q = 0; q < 4; ++q) s4[q] = red[0][q] + red[1][q] + red[2][q] + red[3][q];
  __syncthreads();
  // ---- final w, write (b,q,t,l) ----
  float wq[4] = {0,0,0,0};
  if (act){
    #pragma unroll
    for (int q = 0; q < 4; ++q){
      wq[q] = fm ? (ev[q] / s4[q]) : 0.f;   // ev=0 where ~pm
      wout[(((size_t)(b*4 + q))*NT + t)*NL + tid] = wq[q];
    }
  }
  // ---- wc[q][p] = sum_l w*c, then vc = wc @ Lc + lbc ----
  #pragma unroll
  for (int u = 0; u < 8; ++u){
    float v = wq[u >> 1] * cv[u & 1];
    #pragma unroll
    for (int off = 32; off > 0; off >>= 1) v += __shfl_down(v, off);
    if (lane == 0) red[wave][u] = v;
  }
  __syncthreads();
  float vcv = lbc[tid];
  #pragma unroll
  for (int u = 0; u < 8; ++u){
    float wc8 = red[0][u] + red[1][u] + red[2][u] + red[3][u];
    vcv += wc8 * Lc[u*ND + tid];
  }
  vcwhc[((size_t)b*NT + t)*ND + tid] = vcv;
}

// ---------------- K6: G[b,q] (200x256) = phT[b] @ Lw[q*256:+256] ---------------
__global__ __launch_bounds__(256) void k_gemmG(const float* __restrict__ phT,
    const float* __restrict__ Lw, float* __restrict__ G)
{
  __shared__ float As[16][64];
  __shared__ float Bs[16][64];
  int bq = blockIdx.z; int b = bq >> 2, q = bq & 3;
  int m0 = blockIdx.y*64, n0 = blockIdx.x*64;
  int tid = threadIdx.x;
  int tx = tid & 15, ty = tid >> 4;
  int la_m = tid >> 2, la_k = (tid & 3)*4;
  int lb_k = tid >> 4, lb_n = (tid & 15)*4;
  float acc[4][4] = {};
  for (int kt = 0; kt < 16; ++kt){
    int k0 = kt*16;
    {
      int m = m0 + la_m;
      float4 av = make_float4(0,0,0,0);
      if (m < NL) av = *(const float4*)(phT + ((size_t)b*NL + m)*ND + k0 + la_k);
      As[la_k+0][la_m] = av.x; As[la_k+1][la_m] = av.y;
      As[la_k+2][la_m] = av.z; As[la_k+3][la_m] = av.w;
    }
    {
      int k = k0 + lb_k;
      *(float4*)(&Bs[lb_k][lb_n]) = *(const float4*)(Lw + ((size_t)q*ND + k)*ND + n0 + lb_n);
    }
    __syncthreads();
    #pragma unroll
    for (int k = 0; k < 16; ++k){
      float ra[4], rb[4];
      #pragma unroll
      for (int i = 0; i < 4; ++i) ra[i] = As[k][ty*4 + i];
      #pragma unroll
      for (int j = 0; j < 4; ++j) rb[j] = Bs[k][tx*4 + j];
      #pragma unroll
      for (int i = 0; i < 4; ++i)
        #pragma unroll
        for (int j = 0; j < 4; ++j) acc[i][j] += ra[i]*rb[j];
    }
    __syncthreads();
  }
  #pragma unroll
  for (int i = 0; i < 4; ++i){
    int m = m0 + ty*4 + i;
    if (m >= NL) continue;
    #pragma unroll
    for (int j = 0; j < 4; ++j)
      G[(((size_t)(b*4 + q))*NL + m)*ND + n0 + tx*4 + j] = acc[i][j];
  }
}

// ------- K7: vh[b] (1000x256) = w[b] (1000x800) @ G[b] (800x256); whc in place --
__global__ __launch_bounds__(256) void k_gemmV(const float* __restrict__ wout,
    const float* __restrict__ G, const float* __restrict__ lbw,
    const float* __restrict__ fmv, float* __restrict__ vcwhc)
{
  __shared__ float As[16][64];
  __shared__ float Bs[16][64];
  int b = blockIdx.z;
  int m0 = blockIdx.y*64, n0 = blockIdx.x*64;
  int tid = threadIdx.x;
  int tx = tid & 15, ty = tid >> 4;
  int la_m = tid >> 2, la_k = (tid & 3)*4;
  int lb_k = tid >> 4, lb_n = (tid & 15)*4;
  float acc[4][4] = {};
  for (int kt = 0; kt < 50; ++kt){
    int k0 = kt*16;
    {
      int t = m0 + la_m;
      int k = k0 + la_k;
      int q = k / 200, l = k - q*200;      // float4 never crosses q boundary (200%4==0)
      float4 av = make_float4(0,0,0,0);
      if (t < NT) av = *(const float4*)(wout + (((size_t)(b*4 + q))*NT + t)*NL + l);
      As[la_k+0][la_m] = av.x; As[la_k+1][la_m] = av.y;
      As[la_k+2][la_m] = av.z; As[la_k+3][la_m] = av.w;
    }
    {
      int k = k0 + lb_k;
      int q = k / 200, l = k - q*200;
      *(float4*)(&Bs[lb_k][lb_n]) =
        *(const float4*)(G + (((size_t)(b*4 + q))*NL + l)*ND + n0 + lb_n);
    }
    __syncthreads();
    #pragma unroll
    for (int k = 0; k < 16; ++k){
      float ra[4], rb[4];
      #pragma unroll
      for (int i = 0; i < 4; ++i) ra[i] = As[k][ty*4 + i];
      #pragma unroll
      for (int j = 0; j < 4; ++j) rb[j] = Bs[k][tx*4 + j];
      #pragma unroll
      for (int i = 0; i < 4; ++i)
        #pragma unroll
        for (int j = 0; j < 4; ++j) acc[i][j] += ra[i]*rb[j];
    }
    __syncthreads();
  }
  #pragma unroll
  for (int i = 0; i < 4; ++i){
    int t = m0 + ty*4 + i;
    if (t >= NT) continue;
    float f = fmv[b*NT + t];               // 1.0 / 0.0 frame mask
    #pragma unroll
    for (int j = 0; j < 4; ++j){
      int n = n0 + tx*4 + j;
      size_t idx = ((size_t)b*NT + t)*ND + n;
      vcwhc[idx] = f * (acc[i][j] + lbw[n] + vcwhc[idx]);  // whc = fm ? vh+vc : 0
    }
  }
}

// ------- K8: out (16000x512) = whc @ Wo + bo, stored transposed to (b,s,t) -----
__global__ __launch_bounds__(256) void k_gemmO(const float* __restrict__ whc,
    const float* __restrict__ Wo, const float* __restrict__ bo,
    float* __restrict__ o_mean, float* __restrict__ o_lstd)
{
  __shared__ float As[16][64];
  __shared__ float Bs[16][64];
  int m0 = blockIdx.y*64, n0 = blockIdx.x*64;
  int tid = threadIdx.x;
  int tx = tid & 15, ty = tid >> 4;
  int la_m = tid >> 2, la_k = (tid & 3)*4;
  int lb_k = tid >> 4, lb_n = (tid & 15)*4;
  float acc[4][4] = {};
  for (int kt = 0; kt < 16; ++kt){
    int k0 = kt*16;
    {
      int r = m0 + la_m;
      float4 av = *(const float4*)(whc + (size_t)r*ND + k0 + la_k);
      As[la_k+0][la_m] = av.x; As[la_k+1][la_m] = av.y;
      As[la_k+2][la_m] = av.z; As[la_k+3][la_m] = av.w;
    }
    {
      int k = k0 + lb_k;
      *(float4*)(&Bs[lb_k][lb_n]) = *(const float4*)(Wo + (size_t)k*512 + n0 + lb_n);
    }
    __syncthreads();
    #pragma unroll
    for (int k = 0; k < 16; ++k){
      float ra[4], rb[4];
      #pragma unroll
      for (int i = 0; i < 4; ++i) ra[i] = As[k][ty*4 + i];
      #pragma unroll
      for (int j = 0; j < 4; ++j) rb[j] = Bs[k][tx*4 + j];
      #pragma unroll
      for (int i = 0; i < 4; ++i)
        #pragma unroll
        for (int j = 0; j < 4; ++j) acc[i][j] += ra[i]*rb[j];
    }
    __syncthreads();
  }
  #pragma unroll
  for (int i = 0; i < 4; ++i){
    int r = m0 + ty*4 + i;
    int b = r / NT, t = r - b*NT;
    #pragma unroll
    for (int j = 0; j < 4; ++j){
      int s = n0 + tx*4 + j;
      float v = acc[i][j] + bo[s];
      if (s < ND) o_mean[((size_t)b*ND + s)*NT + t] = v;
      else        o_lstd[((size_t)b*ND + (s - ND))*NT + t] = v;
    }
  }
}

extern "C" void kernel_launch(void* const* d_in, const int* in_sizes, int n_in,
                              void* d_out, int out_size, void* d_ws, size_t ws_size,
                              hipStream_t stream)
{
  const float* dur = (const float*)d_in[0];
  const float* ph  = (const float*)d_in[1];
  // d_in[2] phoneme_mask: unused (pm == durations > 0)
  const float* Wpw = (const float*)d_in[3];
  const float* bpw = (const float*)d_in[4];
  const float* Cw  = (const float*)d_in[5];
  const float* cbw = (const float*)d_in[6];
  const float* Mw  = (const float*)d_in[7];
  const float* mbw = (const float*)d_in[8];
  const float* Lw  = (const float*)d_in[9];
  const float* lbw = (const float*)d_in[10];
  const float* Wpc = (const float*)d_in[11];
  const float* bpc = (const float*)d_in[12];
  const float* Cc  = (const float*)d_in[13];
  const float* cbc = (const float*)d_in[14];
  const float* Mc  = (const float*)d_in[15];
  const float* mbc = (const float*)d_in[16];
  const float* Lc  = (const float*)d_in[17];
  const float* lbc = (const float*)d_in[18];
  const float* Wo  = (const float*)d_in[19];
  const float* bo  = (const float*)d_in[20];

  float* out    = (float*)d_out;
  float* o_mean = out;
  float* o_lstd = out + (size_t)NB*ND*NT;
  float* o_fm   = o_lstd + (size_t)NB*ND*NT;
  float* o_fl   = o_fm + NB*NT;
  float* o_w    = o_fl + NB;

  float* ws    = (float*)d_ws;
  float* phT   = ws + OFF_PHT;
  float* G     = ws + OFF_G;
  float* vcwhc = ws + OFF_VCWHC;
  float* hw    = ws + OFF_HW;
  float* hc    = ws + OFF_HC;
  float* sk    = ws + OFF_SK;
  float* Ew    = ws + OFF_EW;
  float* Ec    = ws + OFF_EC;
  float* bw2   = ws + OFF_BW2;
  float* bc2   = ws + OFF_BC2;
  int*   fl    = (int*)(ws + OFF_FL);

  k_prep<<<NB, 256, 0, stream>>>(dur, sk, fl, o_fm, o_fl);
  k_combine<<<48, 256, 0, stream>>>(Wpw, Cw, bpw, Wpc, Cc, bpc, Ew, Ec, bw2, bc2);
  {
    dim3 g(7, 8, NB), blk(32, 8);
    k_transpose<<<g, blk, 0, stream>>>(ph, phT);
  }
  k_hwc<<<200, 256, 0, stream>>>(phT, dur, Ew, Ec, bw2, bc2, cbw, cbc, hw, hc);
  k_wsoft<<<NB*NT, 256, 0, stream>>>(dur, sk, fl, hw, hc, Mw, mbw, Mc, mbc, Lc, lbc,
                                     o_w, vcwhc);
  {
    dim3 g(4, 4, NB*4);
    k_gemmG<<<g, 256, 0, stream>>>(phT, Lw, G);
  }
  {
    dim3 g(4, 16, NB);
    k_gemmV<<<g, 256, 0, stream>>>(o_w, G, lbw, o_fm, vcwhc);
  }
  {
    dim3 g(8, 250);
    k_gemmO<<<g, 256, 0, stream>>>(vcwhc, Wo, bo, o_mean, o_lstd);
  }
}

// Round 2
// 362.351 us; speedup vs baseline: 1.2306x; 1.2306x over previous
//
#include <hip/hip_runtime.h>
#include <hip/hip_bf16.h>
#include <math.h>

#define NB 16
#define ND 256
#define NL 200
#define NT 1000

typedef unsigned short ushort_t;
typedef __bf16 bf16x8 __attribute__((ext_vector_type(8)));
typedef float f32x4 __attribute__((ext_vector_type(4)));

#define LDS_AS(p) ((__attribute__((address_space(3))) void*)(p))
#define GLB_AS(p) ((const __attribute__((address_space(1))) void*)(p))

// ---- workspace layout (float offsets) ----
#define OFF_PHT   0u         // phT[b][l][d] fp32            819200
#define OFF_VC    819200u    // vc[b][t][d] fp32             4096000
#define OFF_HW    4915200u   // hw[b][l][8]                  25600
#define OFF_HC    4940800u   //                              25600
#define OFF_SK    4966400u   // exclusive cumsum             3200
#define OFF_EW    4969600u   // E[oc][k][d]                  6144
#define OFF_EC    4975744u   //                              6144
#define OFF_BW2   4981888u   //                              24
#define OFF_BC2   4981912u   //                              24
#define OFF_FL    4981936u   // frame_lengths int            16
#define OFF_WBF   4981952u   // w bf16 [b][1024][800]        6553600 floats
#define OFF_GT    11535552u  // Gt bf16 [b][256][800]        1638400 floats
#define OFF_WHC   13173952u  // whc bf16 [16000][256]        2048000 floats
#define OFF_WOT   15221952u  // WoT bf16 [512][256]          65536 floats

__device__ __forceinline__ float silu_f(float x){ return x / (1.f + expf(-x)); }
__device__ __forceinline__ ushort_t f2bf(float x){
  __hip_bfloat16 h = __float2bfloat16(x);
  return *(ushort_t*)&h;
}

// ---------------- K1: durations -> sk, frame_lengths, frame_mask; zero w-pad ---
__global__ __launch_bounds__(256) void k_prep(const float* __restrict__ dur,
    float* __restrict__ sk_ws, int* __restrict__ fl_ws,
    float* __restrict__ o_fm, float* __restrict__ o_fl,
    ushort_t* __restrict__ wbf)
{
  int b = blockIdx.x, tid = threadIdx.x;
  __shared__ float sdur[NL];
  __shared__ float ssk[NL];
  __shared__ int sfl;
  if (tid < NL) sdur[tid] = dur[b*NL + tid];
  __syncthreads();
  if (tid == 0){
    float run = 0.f;
    for (int l = 0; l < NL; ++l){ ssk[l] = run; run += sdur[l]; }
    int fl = (int)rintf(run);            // round-half-even, matches jnp.round
    fl = fl < 0 ? 0 : (fl > NT ? NT : fl);
    sfl = fl; fl_ws[b] = fl; o_fl[b] = (float)fl;
  }
  __syncthreads();
  if (tid < NL) sk_ws[b*NL + tid] = ssk[tid];
  for (int t = tid; t < NT; t += 256) o_fm[b*NT + t] = (t < sfl) ? 1.f : 0.f;
  // zero-pad w_bf16 rows 1000..1023 for this b (MFMA M-padding)
  for (int i = tid; i < 24*800; i += 256){
    int row = 1000 + i/800, col = i - (i/800)*800;
    wbf[((size_t)b*1024 + row)*800 + col] = 0;
  }
}

// ---------------- K2: fold pointwise Wp into conv: E[oc,k,d], bias2[oc,k] ------
__global__ __launch_bounds__(256) void k_combine(
    const float* __restrict__ Wp_w, const float* __restrict__ C_w, const float* __restrict__ bp_w,
    const float* __restrict__ Wp_c, const float* __restrict__ C_c, const float* __restrict__ bp_c,
    float* __restrict__ Ew, float* __restrict__ Ec,
    float* __restrict__ bw2, float* __restrict__ bc2)
{
  int gid = blockIdx.x*256 + threadIdx.x;   // 12288 = 2 * 8*3*256
  int branch = gid / 6144;
  int r = gid % 6144;
  int d = r & 255;
  int ock = r >> 8;            // oc*3+k
  int oc = ock / 3, k = ock % 3;
  const float* Wp = branch ? Wp_c : Wp_w;
  const float* C  = branch ? C_c  : C_w;
  float acc = 0.f;
  for (int i = 0; i < ND; ++i) acc += C[(oc*ND + i)*3 + k] * Wp[i*ND + d];
  (branch ? Ec : Ew)[r] = acc;
  if (d == 0){
    const float* bp = branch ? bp_c : bp_w;
    float bb = 0.f;
    for (int i = 0; i < ND; ++i) bb += C[(oc*ND + i)*3 + k] * bp[i];
    (branch ? bc2 : bw2)[ock] = bb;
  }
}

// ---------------- K3: phoneme (b,d,l) -> phT (b,l,d) ---------------------------
__global__ void k_transpose(const float* __restrict__ ph, float* __restrict__ phT)
{
  __shared__ float tile[32][33];
  int b = blockIdx.z;
  int l0 = blockIdx.x*32, d0 = blockIdx.y*32;
  int tx = threadIdx.x, ty = threadIdx.y;  // 32 x 8
  #pragma unroll
  for (int i = 0; i < 4; ++i){
    int d = d0 + ty + i*8, l = l0 + tx;
    tile[ty + i*8][tx] = (l < NL) ? ph[((size_t)b*ND + d)*NL + l] : 0.f;
  }
  __syncthreads();
  #pragma unroll
  for (int i = 0; i < 4; ++i){
    int l = l0 + ty + i*8, d = d0 + tx;
    if (l < NL) phT[((size_t)b*NL + l)*ND + d] = tile[tx][ty + i*8];
  }
}

// ---------------- K4: hw/hc = silu(conv(pointwise(ph))) * pm -------------------
__global__ __launch_bounds__(256) void k_hwc(const float* __restrict__ phT,
    const float* __restrict__ dur,
    const float* __restrict__ Ew, const float* __restrict__ Ec,
    const float* __restrict__ bw2, const float* __restrict__ bc2,
    const float* __restrict__ cbw, const float* __restrict__ cbc,
    float* __restrict__ hw, float* __restrict__ hc)
{
  int gid = blockIdx.x*256 + threadIdx.x;   // 51200 = 16*200*16
  int b = gid / (NL*16);
  int r = gid % (NL*16);
  int l = r >> 4;
  int u = r & 15;
  int branch = u >> 3, oc = u & 7;
  const float* E  = branch ? Ec  : Ew;
  const float* b2 = branch ? bc2 : bw2;
  float val = (branch ? cbc : cbw)[oc];
  #pragma unroll
  for (int k = 0; k < 3; ++k){
    int ll = l + k - 1;
    if (ll < 0 || ll >= NL) continue;      // SAME zero-padding: drop term+bias
    float acc = b2[oc*3 + k];
    const float* Erow = E + (oc*3 + k)*ND;
    const float* prow = phT + ((size_t)b*NL + ll)*ND;
    for (int d = 0; d < ND; ++d) acc += Erow[d] * prow[d];
    val += acc;
  }
  float pm = (dur[b*NL + l] > 0.5f) ? 1.f : 0.f;
  (branch ? hc : hw)[(b*NL + l)*8 + oc] = silu_f(val) * pm;
}

// ---------------- K5: per (b,t): MLPs, softmax over l, w out (fp32+bf16), vc ---
__global__ __launch_bounds__(256) void k_wsoft(
    const float* __restrict__ dur, const float* __restrict__ sk_ws,
    const int* __restrict__ fl_ws,
    const float* __restrict__ hw, const float* __restrict__ hc,
    const float* __restrict__ Mw, const float* __restrict__ mbw,
    const float* __restrict__ Mc, const float* __restrict__ mbc,
    const float* __restrict__ Lc, const float* __restrict__ lbc,
    float* __restrict__ wout, ushort_t* __restrict__ wbf,
    float* __restrict__ vc)
{
  int bt = blockIdx.x;
  int b = bt / NT, t = bt - b*NT;
  int tid = threadIdx.x;
  int wave = tid >> 6, lane = tid & 63;
  bool fm = t < fl_ws[b];
  bool act = tid < NL;
  __shared__ float red[4][8];

  float z[4] = {0,0,0,0};
  float cv[2] = {0,0};
  float pmf = 0.f;
  if (act){
    float dl = dur[b*NL + tid];
    pmf = (dl > 0.5f) ? 1.f : 0.f;
    bool am = fm && (pmf > 0.f);
    float S  = am ? ((float)(t+1) - sk_ws[b*NL + tid]) : 0.f;
    float Ev = am ? dl : 0.f;
    const float* hwp = hw + (b*NL + tid)*8;
    #pragma unroll
    for (int q = 0; q < 4; ++q){
      float a = mbw[q] + S*Mw[q] + Ev*Mw[4 + q];
      #pragma unroll
      for (int j = 0; j < 8; ++j) a += hwp[j]*Mw[(2 + j)*4 + q];
      z[q] = silu_f(a);
    }
    const float* hcp = hc + (b*NL + tid)*8;
    #pragma unroll
    for (int p = 0; p < 2; ++p){
      float a = mbc[p] + S*Mc[p] + Ev*Mc[2 + p];
      #pragma unroll
      for (int j = 0; j < 8; ++j) a += hcp[j]*Mc[(2 + j)*2 + p];
      cv[p] = silu_f(a);
    }
  }
  bool valid = act && (pmf > 0.f);
  #pragma unroll
  for (int q = 0; q < 4; ++q){
    float v = valid ? z[q] : -INFINITY;
    #pragma unroll
    for (int off = 32; off > 0; off >>= 1) v = fmaxf(v, __shfl_down(v, off));
    if (lane == 0) red[wave][q] = v;
  }
  __syncthreads();
  float m4[4];
  #pragma unroll
  for (int q = 0; q < 4; ++q)
    m4[q] = fmaxf(fmaxf(red[0][q], red[1][q]), fmaxf(red[2][q], red[3][q]));
  __syncthreads();
  float ev[4];
  #pragma unroll
  for (int q = 0; q < 4; ++q){
    ev[q] = valid ? expf(z[q] - m4[q]) : 0.f;
    float v = ev[q];
    #pragma unroll
    for (int off = 32; off > 0; off >>= 1) v += __shfl_down(v, off);
    if (lane == 0) red[wave][q] = v;
  }
  __syncthreads();
  float s4[4];
  #pragma unroll
  for (int q = 0; q < 4; ++q) s4[q] = red[0][q] + red[1][q] + red[2][q] + red[3][q];
  __syncthreads();
  float wq[4] = {0,0,0,0};
  if (act){
    #pragma unroll
    for (int q = 0; q < 4; ++q){
      wq[q] = fm ? (ev[q] / s4[q]) : 0.f;   // ev=0 where ~pm
      wout[(((size_t)(b*4 + q))*NT + t)*NL + tid] = wq[q];
      wbf[((size_t)(b*1024 + t))*800 + q*200 + tid] = f2bf(wq[q]);
    }
  }
  #pragma unroll
  for (int u = 0; u < 8; ++u){
    float v = wq[u >> 1] * cv[u & 1];
    #pragma unroll
    for (int off = 32; off > 0; off >>= 1) v += __shfl_down(v, off);
    if (lane == 0) red[wave][u] = v;
  }
  __syncthreads();
  float vcv = lbc[tid];
  #pragma unroll
  for (int u = 0; u < 8; ++u){
    float wc8 = red[0][u] + red[1][u] + red[2][u] + red[3][u];
    vcv += wc8 * Lc[u*ND + tid];
  }
  vc[((size_t)b*NT + t)*ND + tid] = vcv;
}

// ------ K6: G = phT @ Lw[q-block] (fp32 compute, small) -> Gt bf16 [b][n][k] ---
__global__ __launch_bounds__(256) void k_gemmG(const float* __restrict__ phT,
    const float* __restrict__ Lw, ushort_t* __restrict__ Gt)
{
  __shared__ float As[16][64];
  __shared__ float Bs[16][64];
  int bq = blockIdx.z; int b = bq >> 2, q = bq & 3;
  int m0 = blockIdx.y*64, n0 = blockIdx.x*64;
  int tid = threadIdx.x;
  int tx = tid & 15, ty = tid >> 4;
  int la_m = tid >> 2, la_k = (tid & 3)*4;
  int lb_k = tid >> 4, lb_n = (tid & 15)*4;
  float acc[4][4] = {};
  for (int kt = 0; kt < 16; ++kt){
    int k0 = kt*16;
    {
      int m = m0 + la_m;
      float4 av = make_float4(0,0,0,0);
      if (m < NL) av = *(const float4*)(phT + ((size_t)b*NL + m)*ND + k0 + la_k);
      As[la_k+0][la_m] = av.x; As[la_k+1][la_m] = av.y;
      As[la_k+2][la_m] = av.z; As[la_k+3][la_m] = av.w;
    }
    {
      int k = k0 + lb_k;
      *(float4*)(&Bs[lb_k][lb_n]) = *(const float4*)(Lw + ((size_t)q*ND + k)*ND + n0 + lb_n);
    }
    __syncthreads();
    #pragma unroll
    for (int k = 0; k < 16; ++k){
      float ra[4], rb[4];
      #pragma unroll
      for (int i = 0; i < 4; ++i) ra[i] = As[k][ty*4 + i];
      #pragma unroll
      for (int j = 0; j < 4; ++j) rb[j] = Bs[k][tx*4 + j];
      #pragma unroll
      for (int i = 0; i < 4; ++i)
        #pragma unroll
        for (int j = 0; j < 4; ++j) acc[i][j] += ra[i]*rb[j];
    }
    __syncthreads();
  }
  #pragma unroll
  for (int i = 0; i < 4; ++i){
    int m = m0 + ty*4 + i;
    if (m >= NL) continue;
    #pragma unroll
    for (int j = 0; j < 4; ++j)
      Gt[((size_t)b*ND + n0 + tx*4 + j)*800 + q*NL + m] = f2bf(acc[i][j]);
  }
}

// ---------------- K6b: WoT[n][k] = bf16(Wo[k][n]) ------------------------------
__global__ __launch_bounds__(256) void k_woT(const float* __restrict__ Wo,
                                             ushort_t* __restrict__ WoT)
{
  int gid = blockIdx.x*256 + threadIdx.x;   // 131072
  int n = gid >> 8, k = gid & 255;
  WoT[gid] = f2bf(Wo[(size_t)k*512 + n]);
}

// ------- K7: MFMA vh = w_bf16 @ Gt^T per b; whc = fm*(vh+lbw+vc) -> bf16 -------
// 128x128 block tile, 4 waves (2x2), each wave 64x64 = 4x4 subtiles of 16x16x32.
// LDS layout [kg(4)][row(128)][16B] satisfies global_load_lds contiguity AND
// gives 256B-contiguous ds_read_b128 per 16 lanes (2-way bank alias = free).
__global__ __launch_bounds__(256) void k_gemmV_mfma(
    const ushort_t* __restrict__ wbf,   // [16][1024][800] bf16
    const ushort_t* __restrict__ Gt,    // [16][256][800] bf16
    const float* __restrict__ vc,       // [16][1000][256]
    const float* __restrict__ lbw,      // [256]
    const float* __restrict__ fmv,      // [16][1000]
    ushort_t* __restrict__ whc)         // [16000][256] bf16
{
  __shared__ ushort_t As[4096];   // 8KB: [kg][m][8bf16]
  __shared__ ushort_t Bs[4096];   // 8KB: [kg][n][8bf16]
  int b = blockIdx.z;
  int m0 = blockIdx.y * 128;
  int n0 = blockIdx.x * 128;
  int tid = threadIdx.x, lane = tid & 63, wave = tid >> 6;
  int wm = wave >> 1, wn = wave & 1;
  int col = lane & 15, kg4 = lane >> 4;

  f32x4 acc[4][4] = {};

  for (int kt = 0; kt < 25; ++kt){
    int k0 = kt*32;
    #pragma unroll
    for (int r = 0; r < 2; ++r){
      int o = wave*1024 + r*4096;           // byte offset of this wave's chunk
      int co = o + (lane << 4);
      int kg = co >> 11, row = (co >> 4) & 127;
      const ushort_t* ga = wbf + ((size_t)(b*1024 + m0 + row))*800 + k0 + kg*8;
      __builtin_amdgcn_global_load_lds(GLB_AS(ga), LDS_AS(As + (o >> 1)), 16, 0, 0);
      const ushort_t* gb = Gt + ((size_t)(b*ND + n0 + row))*800 + k0 + kg*8;
      __builtin_amdgcn_global_load_lds(GLB_AS(gb), LDS_AS(Bs + (o >> 1)), 16, 0, 0);
    }
    __builtin_amdgcn_s_waitcnt(0);
    __syncthreads();
    const bf16x8* Av = (const bf16x8*)As;
    const bf16x8* Bv = (const bf16x8*)Bs;
    bf16x8 afr[4], bfr[4];
    #pragma unroll
    for (int i = 0; i < 4; ++i) afr[i] = Av[kg4*128 + wm*64 + i*16 + col];
    #pragma unroll
    for (int j = 0; j < 4; ++j) bfr[j] = Bv[kg4*128 + wn*64 + j*16 + col];
    #pragma unroll
    for (int i = 0; i < 4; ++i)
      #pragma unroll
      for (int j = 0; j < 4; ++j)
        acc[i][j] = __builtin_amdgcn_mfma_f32_16x16x32_bf16(afr[i], bfr[j], acc[i][j], 0, 0, 0);
    __syncthreads();
  }

  int rq = lane >> 4;
  #pragma unroll
  for (int i = 0; i < 4; ++i){
    #pragma unroll
    for (int r = 0; r < 4; ++r){
      int t = m0 + wm*64 + i*16 + rq*4 + r;
      if (t >= NT) continue;
      float f = fmv[b*NT + t];
      #pragma unroll
      for (int j = 0; j < 4; ++j){
        int n = n0 + wn*64 + j*16 + col;
        size_t idx = ((size_t)b*NT + t)*ND + n;
        float v = f * (acc[i][j][r] + lbw[n] + vc[idx]);
        whc[idx] = f2bf(v);
      }
    }
  }
}

// ------- K8: MFMA out = whc_bf16 @ WoT^T + bo, stored transposed (b,s,t) -------
__global__ __launch_bounds__(256) void k_gemmO_mfma(
    const ushort_t* __restrict__ whc,   // [16000][256] bf16
    const ushort_t* __restrict__ WoT,   // [512][256] bf16
    const float* __restrict__ bo,       // [512]
    float* __restrict__ o_mean, float* __restrict__ o_lstd)
{
  __shared__ ushort_t As[4096];
  __shared__ ushort_t Bs[4096];
  int m0 = blockIdx.y * 128;            // over 16000 (125 tiles, exact)
  int n0 = blockIdx.x * 128;            // over 512 (4 tiles)
  int tid = threadIdx.x, lane = tid & 63, wave = tid >> 6;
  int wm = wave >> 1, wn = wave & 1;
  int col = lane & 15, kg4 = lane >> 4;

  f32x4 acc[4][4] = {};

  for (int kt = 0; kt < 8; ++kt){
    int k0 = kt*32;
    #pragma unroll
    for (int r = 0; r < 2; ++r){
      int o = wave*1024 + r*4096;
      int co = o + (lane << 4);
      int kg = co >> 11, row = (co >> 4) & 127;
      const ushort_t* ga = whc + ((size_t)(m0 + row))*ND + k0 + kg*8;
      __builtin_amdgcn_global_load_lds(GLB_AS(ga), LDS_AS(As + (o >> 1)), 16, 0, 0);
      const ushort_t* gb = WoT + ((size_t)(n0 + row))*ND + k0 + kg*8;
      __builtin_amdgcn_global_load_lds(GLB_AS(gb), LDS_AS(Bs + (o >> 1)), 16, 0, 0);
    }
    __builtin_amdgcn_s_waitcnt(0);
    __syncthreads();
    const bf16x8* Av = (const bf16x8*)As;
    const bf16x8* Bv = (const bf16x8*)Bs;
    bf16x8 afr[4], bfr[4];
    #pragma unroll
    for (int i = 0; i < 4; ++i) afr[i] = Av[kg4*128 + wm*64 + i*16 + col];
    #pragma unroll
    for (int j = 0; j < 4; ++j) bfr[j] = Bv[kg4*128 + wn*64 + j*16 + col];
    #pragma unroll
    for (int i = 0; i < 4; ++i)
      #pragma unroll
      for (int j = 0; j < 4; ++j)
        acc[i][j] = __builtin_amdgcn_mfma_f32_16x16x32_bf16(afr[i], bfr[j], acc[i][j], 0, 0, 0);
    __syncthreads();
  }

  int rq = lane >> 4;
  #pragma unroll
  for (int i = 0; i < 4; ++i){
    #pragma unroll
    for (int r = 0; r < 4; ++r){
      int m = m0 + wm*64 + i*16 + rq*4 + r;
      int b = m / NT, t = m - b*NT;
      #pragma unroll
      for (int j = 0; j < 4; ++j){
        int s = n0 + wn*64 + j*16 + col;
        float v = acc[i][j][r] + bo[s];
        if (s < ND) o_mean[((size_t)b*ND + s)*NT + t] = v;
        else        o_lstd[((size_t)b*ND + (s - ND))*NT + t] = v;
      }
    }
  }
}

extern "C" void kernel_launch(void* const* d_in, const int* in_sizes, int n_in,
                              void* d_out, int out_size, void* d_ws, size_t ws_size,
                              hipStream_t stream)
{
  const float* dur = (const float*)d_in[0];
  const float* ph  = (const float*)d_in[1];
  // d_in[2] phoneme_mask: unused (pm == durations > 0)
  const float* Wpw = (const float*)d_in[3];
  const float* bpw = (const float*)d_in[4];
  const float* Cw  = (const float*)d_in[5];
  const float* cbw = (const float*)d_in[6];
  const float* Mw  = (const float*)d_in[7];
  const float* mbw = (const float*)d_in[8];
  const float* Lw  = (const float*)d_in[9];
  const float* lbw = (const float*)d_in[10];
  const float* Wpc = (const float*)d_in[11];
  const float* bpc = (const float*)d_in[12];
  const float* Cc  = (const float*)d_in[13];
  const float* cbc = (const float*)d_in[14];
  const float* Mc  = (const float*)d_in[15];
  const float* mbc = (const float*)d_in[16];
  const float* Lc  = (const float*)d_in[17];
  const float* lbc = (const float*)d_in[18];
  const float* Wo  = (const float*)d_in[19];
  const float* bo  = (const float*)d_in[20];

  float* out    = (float*)d_out;
  float* o_mean = out;
  float* o_lstd = out + (size_t)NB*ND*NT;
  float* o_fm   = o_lstd + (size_t)NB*ND*NT;
  float* o_fl   = o_fm + NB*NT;
  float* o_w    = o_fl + NB;

  float* ws   = (float*)d_ws;
  float* phT  = ws + OFF_PHT;
  float* vc   = ws + OFF_VC;
  float* hw   = ws + OFF_HW;
  float* hc   = ws + OFF_HC;
  float* sk   = ws + OFF_SK;
  float* Ew   = ws + OFF_EW;
  float* Ec   = ws + OFF_EC;
  float* bw2  = ws + OFF_BW2;
  float* bc2  = ws + OFF_BC2;
  int*   fl   = (int*)(ws + OFF_FL);
  ushort_t* wbf  = (ushort_t*)(ws + OFF_WBF);
  ushort_t* Gt   = (ushort_t*)(ws + OFF_GT);
  ushort_t* whc  = (ushort_t*)(ws + OFF_WHC);
  ushort_t* WoT  = (ushort_t*)(ws + OFF_WOT);

  k_prep<<<NB, 256, 0, stream>>>(dur, sk, fl, o_fm, o_fl, wbf);
  k_combine<<<48, 256, 0, stream>>>(Wpw, Cw, bpw, Wpc, Cc, bpc, Ew, Ec, bw2, bc2);
  {
    dim3 g(7, 8, NB), blk(32, 8);
    k_transpose<<<g, blk, 0, stream>>>(ph, phT);
  }
  k_hwc<<<200, 256, 0, stream>>>(phT, dur, Ew, Ec, bw2, bc2, cbw, cbc, hw, hc);
  k_woT<<<512, 256, 0, stream>>>(Wo, WoT);
  k_wsoft<<<NB*NT, 256, 0, stream>>>(dur, sk, fl, hw, hc, Mw, mbw, Mc, mbc, Lc, lbc,
                                     o_w, wbf, vc);
  {
    dim3 g(4, 4, NB*4);
    k_gemmG<<<g, 256, 0, stream>>>(phT, Lw, Gt);
  }
  {
    dim3 g(2, 8, NB);
    k_gemmV_mfma<<<g, 256, 0, stream>>>(wbf, Gt, vc, lbw, o_fm, whc);
  }
  {
    dim3 g(4, 125);
    k_gemmO_mfma<<<g, 256, 0, stream>>>(whc, WoT, bo, o_mean, o_lstd);
  }
}

// Round 3
// 317.954 us; speedup vs baseline: 1.4024x; 1.1396x over previous
//
#include <hip/hip_runtime.h>
#include <hip/hip_bf16.h>
#include <math.h>

#define NB 16
#define ND 256
#define NL 200
#define NT 1000

typedef unsigned short ushort_t;
typedef __bf16 bf16x8 __attribute__((ext_vector_type(8)));
typedef float f32x4 __attribute__((ext_vector_type(4)));

#define LDS_AS(p) ((__attribute__((address_space(3))) void*)(p))
#define GLB_AS(p) ((const __attribute__((address_space(1))) void*)(p))

// ---- workspace layout (float offsets) ----
#define OFF_PHT   0u         // phT[b][l][d] fp32            819200
#define OFF_VC    819200u    // vc[b][t][d] fp32             4096000
#define OFF_HW    4915200u   // hw[b][l][8]                  25600
#define OFF_HC    4940800u   //                              25600
#define OFF_SK    4966400u   // exclusive cumsum             3200
#define OFF_EW    4969600u   // E[oc][k][d]                  6144
#define OFF_EC    4975744u   //                              6144
#define OFF_BW2   4981888u   //                              24
#define OFF_BC2   4981912u   //                              24
#define OFF_FL    4981936u   // frame_lengths int            16
#define OFF_WBF   4981952u   // w bf16 [b][1024][800]        6553600 floats
#define OFF_GT    11535552u  // Gt bf16 [b][256][800]        1638400 floats
#define OFF_WHC   13173952u  // whc bf16 [16000][256]        2048000 floats
#define OFF_WOT   15221952u  // WoT bf16 [512][256]          65536 floats
#define OFF_BASE  15287488u  // base[b][256][8] fp32         32768 floats

__device__ __forceinline__ float silu_f(float x){ return x / (1.f + expf(-x)); }
__device__ __forceinline__ ushort_t f2bf(float x){
  __hip_bfloat16 h = __float2bfloat16(x);
  return *(ushort_t*)&h;
}

// ---------------- K1: durations -> sk, frame_lengths, frame_mask ----------------
__global__ __launch_bounds__(256) void k_prep(const float* __restrict__ dur,
    float* __restrict__ sk_ws, int* __restrict__ fl_ws,
    float* __restrict__ o_fm, float* __restrict__ o_fl)
{
  int b = blockIdx.x, tid = threadIdx.x;
  __shared__ float sdur[NL];
  __shared__ float ssk[NL];
  __shared__ int sfl;
  if (tid < NL) sdur[tid] = dur[b*NL + tid];
  __syncthreads();
  if (tid == 0){
    float run = 0.f;
    for (int l = 0; l < NL; ++l){ ssk[l] = run; run += sdur[l]; }
    int fl = (int)rintf(run);            // round-half-even, matches jnp.round
    fl = fl < 0 ? 0 : (fl > NT ? NT : fl);
    sfl = fl; fl_ws[b] = fl; o_fl[b] = (float)fl;
  }
  __syncthreads();
  if (tid < NL) sk_ws[b*NL + tid] = ssk[tid];
  for (int t = tid; t < NT; t += 256) o_fm[b*NT + t] = (t < sfl) ? 1.f : 0.f;
}

// ---------------- K2: fold pointwise Wp into conv: E[oc,k,d], bias2[oc,k] ------
__global__ __launch_bounds__(256) void k_combine(
    const float* __restrict__ Wp_w, const float* __restrict__ C_w, const float* __restrict__ bp_w,
    const float* __restrict__ Wp_c, const float* __restrict__ C_c, const float* __restrict__ bp_c,
    float* __restrict__ Ew, float* __restrict__ Ec,
    float* __restrict__ bw2, float* __restrict__ bc2)
{
  int gid = blockIdx.x*256 + threadIdx.x;   // 12288 = 2 * 8*3*256
  int branch = gid / 6144;
  int r = gid % 6144;
  int d = r & 255;
  int ock = r >> 8;            // oc*3+k
  int oc = ock / 3, k = ock % 3;
  const float* Wp = branch ? Wp_c : Wp_w;
  const float* C  = branch ? C_c  : C_w;
  float acc = 0.f;
  for (int i = 0; i < ND; ++i) acc += C[(oc*ND + i)*3 + k] * Wp[i*ND + d];
  (branch ? Ec : Ew)[r] = acc;
  if (d == 0){
    const float* bp = branch ? bp_c : bp_w;
    float bb = 0.f;
    for (int i = 0; i < ND; ++i) bb += C[(oc*ND + i)*3 + k] * bp[i];
    (branch ? bc2 : bw2)[ock] = bb;
  }
}

// ---------------- K3: phoneme (b,d,l) -> phT (b,l,d) ---------------------------
__global__ void k_transpose(const float* __restrict__ ph, float* __restrict__ phT)
{
  __shared__ float tile[32][33];
  int b = blockIdx.z;
  int l0 = blockIdx.x*32, d0 = blockIdx.y*32;
  int tx = threadIdx.x, ty = threadIdx.y;  // 32 x 8
  #pragma unroll
  for (int i = 0; i < 4; ++i){
    int d = d0 + ty + i*8, l = l0 + tx;
    tile[ty + i*8][tx] = (l < NL) ? ph[((size_t)b*ND + d)*NL + l] : 0.f;
  }
  __syncthreads();
  #pragma unroll
  for (int i = 0; i < 4; ++i){
    int l = l0 + ty + i*8, d = d0 + tx;
    if (l < NL) phT[((size_t)b*NL + l)*ND + d] = tile[tx][ty + i*8];
  }
}

// ---------------- K4: hw/hc = silu(conv(pointwise(ph))) * pm -------------------
__global__ __launch_bounds__(256) void k_hwc(const float* __restrict__ phT,
    const float* __restrict__ dur,
    const float* __restrict__ Ew, const float* __restrict__ Ec,
    const float* __restrict__ bw2, const float* __restrict__ bc2,
    const float* __restrict__ cbw, const float* __restrict__ cbc,
    float* __restrict__ hw, float* __restrict__ hc)
{
  int gid = blockIdx.x*256 + threadIdx.x;   // 51200 = 16*200*16
  int b = gid / (NL*16);
  int r = gid % (NL*16);
  int l = r >> 4;
  int u = r & 15;
  int branch = u >> 3, oc = u & 7;
  const float* E  = branch ? Ec  : Ew;
  const float* b2 = branch ? bc2 : bw2;
  float val = (branch ? cbc : cbw)[oc];
  #pragma unroll
  for (int k = 0; k < 3; ++k){
    int ll = l + k - 1;
    if (ll < 0 || ll >= NL) continue;      // SAME zero-padding: drop term+bias
    float acc = b2[oc*3 + k];
    const float* Erow = E + (oc*3 + k)*ND;
    const float* prow = phT + ((size_t)b*NL + ll)*ND;
    for (int d = 0; d < ND; ++d) acc += Erow[d] * prow[d];
    val += acc;
  }
  float pm = (dur[b*NL + l] > 0.5f) ? 1.f : 0.f;
  (branch ? hc : hw)[(b*NL + l)*8 + oc] = silu_f(val) * pm;
}

// ---------------- K4b: t-invariant MLP bases per (b,l) -------------------------
// base[b][l] = float8: {c1w[0..3]}, {c1c[0..1], pm, 0}
// c1w[q] = mbw[q] + dur*Mw[1,q] - sk*Mw[0,q] + sum_j h[j]*Mw[2+j,q]
__global__ __launch_bounds__(256) void k_base(
    const float* __restrict__ dur, const float* __restrict__ sk_ws,
    const float* __restrict__ hw, const float* __restrict__ hc,
    const float* __restrict__ Mw, const float* __restrict__ mbw,
    const float* __restrict__ Mc, const float* __restrict__ mbc,
    float4* __restrict__ base)
{
  int gid = blockIdx.x*256 + threadIdx.x;   // 16*256
  int b = gid >> 8, l = gid & 255;
  float4 o0 = make_float4(0,0,0,0);
  float4 o1 = make_float4(0,0,0,0);
  if (l < NL){
    float dl  = dur[b*NL + l];
    float pm  = (dl > 0.5f) ? 1.f : 0.f;
    float skl = sk_ws[b*NL + l];
    float c1[4], c2[2];
    #pragma unroll
    for (int q = 0; q < 4; ++q) c1[q] = mbw[q] + dl*Mw[4 + q] - skl*Mw[q];
    #pragma unroll
    for (int p = 0; p < 2; ++p) c2[p] = mbc[p] + dl*Mc[2 + p] - skl*Mc[p];
    const float* hwp = hw + (b*NL + l)*8;
    const float* hcp = hc + (b*NL + l)*8;
    #pragma unroll
    for (int j = 0; j < 8; ++j){
      #pragma unroll
      for (int q = 0; q < 4; ++q) c1[q] += hwp[j]*Mw[(2 + j)*4 + q];
      #pragma unroll
      for (int p = 0; p < 2; ++p) c2[p] += hcp[j]*Mc[(2 + j)*2 + p];
    }
    o0 = make_float4(c1[0], c1[1], c1[2], c1[3]);
    o1 = make_float4(c2[0], c2[1], pm, 0.f);
  }
  base[(size_t)gid*2 + 0] = o0;
  base[(size_t)gid*2 + 1] = o1;
}

// ---------------- K5: one wave per t: softmax over l, w out, vc ----------------
__global__ __launch_bounds__(256) void k_wsoft2(
    const float4* __restrict__ base,
    const int* __restrict__ fl_ws,
    const float* __restrict__ Mw, const float* __restrict__ Mc,
    const float* __restrict__ Lc, const float* __restrict__ lbc,
    float* __restrict__ wout, ushort_t* __restrict__ wbf,
    float* __restrict__ vc)
{
  int b = blockIdx.y;
  int wave = threadIdx.x >> 6, lane = threadIdx.x & 63;
  int t = blockIdx.x*4 + wave;
  int fl = fl_ws[b];

  if (t >= fl){
    // masked frame: w rows are exactly 0; wbf/vc left as-is (consumed ×fm=0)
    #pragma unroll
    for (int q = 0; q < 4; ++q){
      #pragma unroll
      for (int c = 0; c < 4; ++c){
        int l = c*64 + lane;
        if (l < NL) wout[(((size_t)(b*4 + q))*NT + t)*NL + l] = 0.f;
      }
    }
    return;
  }

  float t1 = (float)(t + 1);
  float tqw[4], tqc[2];
  #pragma unroll
  for (int q = 0; q < 4; ++q) tqw[q] = t1 * Mw[q];
  #pragma unroll
  for (int p = 0; p < 2; ++p) tqc[p] = t1 * Mc[p];

  float z[4][4], cv[4][2], msk[4];
  float m[4] = {-INFINITY, -INFINITY, -INFINITY, -INFINITY};
  #pragma unroll
  for (int c = 0; c < 4; ++c){
    int l = c*64 + lane;
    float4 b0 = base[((size_t)(b*256 + l))*2 + 0];
    float4 b1 = base[((size_t)(b*256 + l))*2 + 1];
    float pm = b1.z;
    msk[c] = pm;
    float zz[4] = { b0.x + tqw[0], b0.y + tqw[1], b0.z + tqw[2], b0.w + tqw[3] };
    #pragma unroll
    for (int q = 0; q < 4; ++q){
      float s = silu_f(zz[q]);
      z[c][q] = (pm > 0.f) ? s : -INFINITY;
      m[q] = fmaxf(m[q], z[c][q]);
    }
    cv[c][0] = silu_f(b1.x + tqc[0]);
    cv[c][1] = silu_f(b1.y + tqc[1]);
  }
  #pragma unroll
  for (int q = 0; q < 4; ++q){
    float v = m[q];
    #pragma unroll
    for (int off = 32; off; off >>= 1) v = fmaxf(v, __shfl_xor(v, off));
    m[q] = v;
  }
  float s4[4] = {0,0,0,0};
  #pragma unroll
  for (int c = 0; c < 4; ++c){
    #pragma unroll
    for (int q = 0; q < 4; ++q){
      float e = (msk[c] > 0.f) ? expf(z[c][q] - m[q]) : 0.f;
      z[c][q] = e;
      s4[q] += e;
    }
  }
  #pragma unroll
  for (int q = 0; q < 4; ++q){
    float v = s4[q];
    #pragma unroll
    for (int off = 32; off; off >>= 1) v += __shfl_xor(v, off);
    s4[q] = 1.f / v;
  }
  float wc[8] = {0,0,0,0,0,0,0,0};
  #pragma unroll
  for (int c = 0; c < 4; ++c){
    int l = c*64 + lane;
    bool lv = l < NL;
    #pragma unroll
    for (int q = 0; q < 4; ++q){
      float wq = z[c][q] * s4[q];
      if (lv){
        wout[(((size_t)(b*4 + q))*NT + t)*NL + l] = wq;
        wbf[((size_t)(b*1024 + t))*800 + q*200 + l] = f2bf(wq);
      }
      wc[q*2 + 0] += wq * cv[c][0];
      wc[q*2 + 1] += wq * cv[c][1];
    }
  }
  #pragma unroll
  for (int u = 0; u < 8; ++u){
    float v = wc[u];
    #pragma unroll
    for (int off = 32; off; off >>= 1) v += __shfl_xor(v, off);
    wc[u] = v;
  }
  #pragma unroll
  for (int c = 0; c < 4; ++c){
    int d = c*64 + lane;
    float v = lbc[d];
    #pragma unroll
    for (int u = 0; u < 8; ++u) v += wc[u] * Lc[u*ND + d];
    vc[((size_t)b*NT + t)*ND + d] = v;
  }
}

// ------ K6: G = phT @ Lw[q-block] (fp32 compute, small) -> Gt bf16 [b][n][k] ---
__global__ __launch_bounds__(256) void k_gemmG(const float* __restrict__ phT,
    const float* __restrict__ Lw, ushort_t* __restrict__ Gt)
{
  __shared__ float As[16][64];
  __shared__ float Bs[16][64];
  int bq = blockIdx.z; int b = bq >> 2, q = bq & 3;
  int m0 = blockIdx.y*64, n0 = blockIdx.x*64;
  int tid = threadIdx.x;
  int tx = tid & 15, ty = tid >> 4;
  int la_m = tid >> 2, la_k = (tid & 3)*4;
  int lb_k = tid >> 4, lb_n = (tid & 15)*4;
  float acc[4][4] = {};
  for (int kt = 0; kt < 16; ++kt){
    int k0 = kt*16;
    {
      int m = m0 + la_m;
      float4 av = make_float4(0,0,0,0);
      if (m < NL) av = *(const float4*)(phT + ((size_t)b*NL + m)*ND + k0 + la_k);
      As[la_k+0][la_m] = av.x; As[la_k+1][la_m] = av.y;
      As[la_k+2][la_m] = av.z; As[la_k+3][la_m] = av.w;
    }
    {
      int k = k0 + lb_k;
      *(float4*)(&Bs[lb_k][lb_n]) = *(const float4*)(Lw + ((size_t)q*ND + k)*ND + n0 + lb_n);
    }
    __syncthreads();
    #pragma unroll
    for (int k = 0; k < 16; ++k){
      float ra[4], rb[4];
      #pragma unroll
      for (int i = 0; i < 4; ++i) ra[i] = As[k][ty*4 + i];
      #pragma unroll
      for (int j = 0; j < 4; ++j) rb[j] = Bs[k][tx*4 + j];
      #pragma unroll
      for (int i = 0; i < 4; ++i)
        #pragma unroll
        for (int j = 0; j < 4; ++j) acc[i][j] += ra[i]*rb[j];
    }
    __syncthreads();
  }
  #pragma unroll
  for (int i = 0; i < 4; ++i){
    int m = m0 + ty*4 + i;
    if (m >= NL) continue;
    #pragma unroll
    for (int j = 0; j < 4; ++j)
      Gt[((size_t)b*ND + n0 + tx*4 + j)*800 + q*NL + m] = f2bf(acc[i][j]);
  }
}

// ---------------- K6b: WoT[n][k] = bf16(Wo[k][n]) ------------------------------
__global__ __launch_bounds__(256) void k_woT(const float* __restrict__ Wo,
                                             ushort_t* __restrict__ WoT)
{
  int gid = blockIdx.x*256 + threadIdx.x;   // 131072
  int n = gid >> 8, k = gid & 255;
  WoT[gid] = f2bf(Wo[(size_t)k*512 + n]);
}

// ------- K7: MFMA vh = w_bf16 @ Gt^T per b; whc = fm*(vh+lbw+vc) -> bf16 -------
__global__ __launch_bounds__(256) void k_gemmV_mfma(
    const ushort_t* __restrict__ wbf,   // [16][1024][800] bf16
    const ushort_t* __restrict__ Gt,    // [16][256][800] bf16
    const float* __restrict__ vc,       // [16][1000][256]
    const float* __restrict__ lbw,      // [256]
    const float* __restrict__ fmv,      // [16][1000]
    ushort_t* __restrict__ whc)         // [16000][256] bf16
{
  __shared__ ushort_t As[4096];   // 8KB: [kg][m][8bf16]
  __shared__ ushort_t Bs[4096];   // 8KB: [kg][n][8bf16]
  int b = blockIdx.z;
  int m0 = blockIdx.y * 128;
  int n0 = blockIdx.x * 128;
  int tid = threadIdx.x, lane = tid & 63, wave = tid >> 6;
  int wm = wave >> 1, wn = wave & 1;
  int col = lane & 15, kg4 = lane >> 4;

  f32x4 acc[4][4] = {};

  for (int kt = 0; kt < 25; ++kt){
    int k0 = kt*32;
    #pragma unroll
    for (int r = 0; r < 2; ++r){
      int o = wave*1024 + r*4096;           // byte offset of this wave's chunk
      int co = o + (lane << 4);
      int kg = co >> 11, row = (co >> 4) & 127;
      const ushort_t* ga = wbf + ((size_t)(b*1024 + m0 + row))*800 + k0 + kg*8;
      __builtin_amdgcn_global_load_lds(GLB_AS(ga), LDS_AS(As + (o >> 1)), 16, 0, 0);
      const ushort_t* gb = Gt + ((size_t)(b*ND + n0 + row))*800 + k0 + kg*8;
      __builtin_amdgcn_global_load_lds(GLB_AS(gb), LDS_AS(Bs + (o >> 1)), 16, 0, 0);
    }
    __builtin_amdgcn_s_waitcnt(0);
    __syncthreads();
    const bf16x8* Av = (const bf16x8*)As;
    const bf16x8* Bv = (const bf16x8*)Bs;
    bf16x8 afr[4], bfr[4];
    #pragma unroll
    for (int i = 0; i < 4; ++i) afr[i] = Av[kg4*128 + wm*64 + i*16 + col];
    #pragma unroll
    for (int j = 0; j < 4; ++j) bfr[j] = Bv[kg4*128 + wn*64 + j*16 + col];
    #pragma unroll
    for (int i = 0; i < 4; ++i)
      #pragma unroll
      for (int j = 0; j < 4; ++j)
        acc[i][j] = __builtin_amdgcn_mfma_f32_16x16x32_bf16(afr[i], bfr[j], acc[i][j], 0, 0, 0);
    __syncthreads();
  }

  int rq = lane >> 4;
  #pragma unroll
  for (int i = 0; i < 4; ++i){
    #pragma unroll
    for (int r = 0; r < 4; ++r){
      int t = m0 + wm*64 + i*16 + rq*4 + r;
      if (t >= NT) continue;
      float f = fmv[b*NT + t];
      #pragma unroll
      for (int j = 0; j < 4; ++j){
        int n = n0 + wn*64 + j*16 + col;
        size_t idx = ((size_t)b*NT + t)*ND + n;
        float v = f * (acc[i][j][r] + lbw[n] + vc[idx]);
        whc[idx] = f2bf(v);
      }
    }
  }
}

// ------- K8: MFMA out = whc_bf16 @ WoT^T + bo, stored transposed (b,s,t) -------
__global__ __launch_bounds__(256) void k_gemmO_mfma(
    const ushort_t* __restrict__ whc,   // [16000][256] bf16
    const ushort_t* __restrict__ WoT,   // [512][256] bf16
    const float* __restrict__ bo,       // [512]
    float* __restrict__ o_mean, float* __restrict__ o_lstd)
{
  __shared__ ushort_t As[4096];
  __shared__ ushort_t Bs[4096];
  int m0 = blockIdx.y * 128;            // over 16000 (125 tiles, exact)
  int n0 = blockIdx.x * 128;            // over 512 (4 tiles)
  int tid = threadIdx.x, lane = tid & 63, wave = tid >> 6;
  int wm = wave >> 1, wn = wave & 1;
  int col = lane & 15, kg4 = lane >> 4;

  f32x4 acc[4][4] = {};

  for (int kt = 0; kt < 8; ++kt){
    int k0 = kt*32;
    #pragma unroll
    for (int r = 0; r < 2; ++r){
      int o = wave*1024 + r*4096;
      int co = o + (lane << 4);
      int kg = co >> 11, row = (co >> 4) & 127;
      const ushort_t* ga = whc + ((size_t)(m0 + row))*ND + k0 + kg*8;
      __builtin_amdgcn_global_load_lds(GLB_AS(ga), LDS_AS(As + (o >> 1)), 16, 0, 0);
      const ushort_t* gb = WoT + ((size_t)(n0 + row))*ND + k0 + kg*8;
      __builtin_amdgcn_global_load_lds(GLB_AS(gb), LDS_AS(Bs + (o >> 1)), 16, 0, 0);
    }
    __builtin_amdgcn_s_waitcnt(0);
    __syncthreads();
    const bf16x8* Av = (const bf16x8*)As;
    const bf16x8* Bv = (const bf16x8*)Bs;
    bf16x8 afr[4], bfr[4];
    #pragma unroll
    for (int i = 0; i < 4; ++i) afr[i] = Av[kg4*128 + wm*64 + i*16 + col];
    #pragma unroll
    for (int j = 0; j < 4; ++j) bfr[j] = Bv[kg4*128 + wn*64 + j*16 + col];
    #pragma unroll
    for (int i = 0; i < 4; ++i)
      #pragma unroll
      for (int j = 0; j < 4; ++j)
        acc[i][j] = __builtin_amdgcn_mfma_f32_16x16x32_bf16(afr[i], bfr[j], acc[i][j], 0, 0, 0);
    __syncthreads();
  }

  int rq = lane >> 4;
  #pragma unroll
  for (int i = 0; i < 4; ++i){
    #pragma unroll
    for (int r = 0; r < 4; ++r){
      int m = m0 + wm*64 + i*16 + rq*4 + r;
      int b = m / NT, t = m - b*NT;
      #pragma unroll
      for (int j = 0; j < 4; ++j){
        int s = n0 + wn*64 + j*16 + col;
        float v = acc[i][j][r] + bo[s];
        if (s < ND) o_mean[((size_t)b*ND + s)*NT + t] = v;
        else        o_lstd[((size_t)b*ND + (s - ND))*NT + t] = v;
      }
    }
  }
}

extern "C" void kernel_launch(void* const* d_in, const int* in_sizes, int n_in,
                              void* d_out, int out_size, void* d_ws, size_t ws_size,
                              hipStream_t stream)
{
  const float* dur = (const float*)d_in[0];
  const float* ph  = (const float*)d_in[1];
  // d_in[2] phoneme_mask: unused (pm == durations > 0)
  const float* Wpw = (const float*)d_in[3];
  const float* bpw = (const float*)d_in[4];
  const float* Cw  = (const float*)d_in[5];
  const float* cbw = (const float*)d_in[6];
  const float* Mw  = (const float*)d_in[7];
  const float* mbw = (const float*)d_in[8];
  const float* Lw  = (const float*)d_in[9];
  const float* lbw = (const float*)d_in[10];
  const float* Wpc = (const float*)d_in[11];
  const float* bpc = (const float*)d_in[12];
  const float* Cc  = (const float*)d_in[13];
  const float* cbc = (const float*)d_in[14];
  const float* Mc  = (const float*)d_in[15];
  const float* mbc = (const float*)d_in[16];
  const float* Lc  = (const float*)d_in[17];
  const float* lbc = (const float*)d_in[18];
  const float* Wo  = (const float*)d_in[19];
  const float* bo  = (const float*)d_in[20];

  float* out    = (float*)d_out;
  float* o_mean = out;
  float* o_lstd = out + (size_t)NB*ND*NT;
  float* o_fm   = o_lstd + (size_t)NB*ND*NT;
  float* o_fl   = o_fm + NB*NT;
  float* o_w    = o_fl + NB;

  float* ws   = (float*)d_ws;
  float* phT  = ws + OFF_PHT;
  float* vc   = ws + OFF_VC;
  float* hw   = ws + OFF_HW;
  float* hc   = ws + OFF_HC;
  float* sk   = ws + OFF_SK;
  float* Ew   = ws + OFF_EW;
  float* Ec   = ws + OFF_EC;
  float* bw2  = ws + OFF_BW2;
  float* bc2  = ws + OFF_BC2;
  int*   fl   = (int*)(ws + OFF_FL);
  ushort_t* wbf  = (ushort_t*)(ws + OFF_WBF);
  ushort_t* Gt   = (ushort_t*)(ws + OFF_GT);
  ushort_t* whc  = (ushort_t*)(ws + OFF_WHC);
  ushort_t* WoT  = (ushort_t*)(ws + OFF_WOT);
  float4*   base = (float4*)(ws + OFF_BASE);

  k_prep<<<NB, 256, 0, stream>>>(dur, sk, fl, o_fm, o_fl);
  k_combine<<<48, 256, 0, stream>>>(Wpw, Cw, bpw, Wpc, Cc, bpc, Ew, Ec, bw2, bc2);
  {
    dim3 g(7, 8, NB), blk(32, 8);
    k_transpose<<<g, blk, 0, stream>>>(ph, phT);
  }
  k_hwc<<<200, 256, 0, stream>>>(phT, dur, Ew, Ec, bw2, bc2, cbw, cbc, hw, hc);
  k_woT<<<512, 256, 0, stream>>>(Wo, WoT);
  k_base<<<16, 256, 0, stream>>>(dur, sk, hw, hc, Mw, mbw, Mc, mbc, base);
  {
    dim3 g(250, NB);
    k_wsoft2<<<g, 256, 0, stream>>>(base, fl, Mw, Mc, Lc, lbc, o_w, wbf, vc);
  }
  {
    dim3 g(4, 4, NB*4);
    k_gemmG<<<g, 256, 0, stream>>>(phT, Lw, Gt);
  }
  {
    dim3 g(2, 8, NB);
    k_gemmV_mfma<<<g, 256, 0, stream>>>(wbf, Gt, vc, lbw, o_fm, whc);
  }
  {
    dim3 g(4, 125);
    k_gemmO_mfma<<<g, 256, 0, stream>>>(whc, WoT, bo, o_mean, o_lstd);
  }
}

// Round 4
// 295.348 us; speedup vs baseline: 1.5097x; 1.0765x over previous
//
#include <hip/hip_runtime.h>
#include <hip/hip_bf16.h>
#include <math.h>

#define NB 16
#define ND 256
#define NL 200
#define NT 1000

typedef unsigned short ushort_t;
typedef __bf16 bf16x8 __attribute__((ext_vector_type(8)));
typedef float f32x4 __attribute__((ext_vector_type(4)));

#define LDS_AS(p) ((__attribute__((address_space(3))) void*)(p))
#define GLB_AS(p) ((const __attribute__((address_space(1))) void*)(p))

// ---- workspace layout (float offsets) ----
#define OFF_PHT   0u         // phT[b][l][d] fp32            819200
#define OFF_VC    819200u    // vc[b][t][d] fp32             4096000
#define OFF_HW    4915200u   // hw[b][l][8]                  25600
#define OFF_HC    4940800u   //                              25600
#define OFF_SK    4966400u   // exclusive cumsum             3200
#define OFF_EW    4969600u   // E[oc][k][d]                  6144
#define OFF_EC    4975744u   //                              6144
#define OFF_BW2   4981888u   //                              24
#define OFF_BC2   4981912u   //                              24
#define OFF_FL    4981936u   // frame_lengths int            16
#define OFF_WBF   4981952u   // w bf16 [b][1024][800]        6553600 floats
#define OFF_GT    11535552u  // Gt bf16 [b][256][800]        1638400 floats
#define OFF_WHC   13173952u  // whc bf16 [16000][256]        2048000 floats
#define OFF_WOT   15221952u  // WoT bf16 [512][256]          65536 floats
#define OFF_BASE  15287488u  // base[b][256][8] fp32         32768 floats
#define OFF_PHTB  15320256u  // phTb bf16 [b][256pad][256]   524288 floats
#define OFF_LWT   15844544u  // LwT bf16 [4][256][256]       131072 floats

__device__ __forceinline__ float silu_f(float x){ return x / (1.f + expf(-x)); }
__device__ __forceinline__ ushort_t f2bf(float x){
  __hip_bfloat16 h = __float2bfloat16(x);
  return *(ushort_t*)&h;
}

// ---------------- K1: durations -> sk, frame_lengths, frame_mask ----------------
__global__ __launch_bounds__(256) void k_prep(const float* __restrict__ dur,
    float* __restrict__ sk_ws, int* __restrict__ fl_ws,
    float* __restrict__ o_fm, float* __restrict__ o_fl)
{
  int b = blockIdx.x, tid = threadIdx.x;
  __shared__ float sdur[NL];
  __shared__ float ssk[NL];
  __shared__ int sfl;
  if (tid < NL) sdur[tid] = dur[b*NL + tid];
  __syncthreads();
  if (tid == 0){
    float run = 0.f;
    for (int l = 0; l < NL; ++l){ ssk[l] = run; run += sdur[l]; }
    int fl = (int)rintf(run);            // round-half-even, matches jnp.round
    fl = fl < 0 ? 0 : (fl > NT ? NT : fl);
    sfl = fl; fl_ws[b] = fl; o_fl[b] = (float)fl;
  }
  __syncthreads();
  if (tid < NL) sk_ws[b*NL + tid] = ssk[tid];
  for (int t = tid; t < NT; t += 256) o_fm[b*NT + t] = (t < sfl) ? 1.f : 0.f;
}

// ---------------- K2: fold pointwise Wp into conv: E[oc,k,d], bias2[oc,k] ------
__global__ __launch_bounds__(256) void k_combine(
    const float* __restrict__ Wp_w, const float* __restrict__ C_w, const float* __restrict__ bp_w,
    const float* __restrict__ Wp_c, const float* __restrict__ C_c, const float* __restrict__ bp_c,
    float* __restrict__ Ew, float* __restrict__ Ec,
    float* __restrict__ bw2, float* __restrict__ bc2)
{
  int gid = blockIdx.x*256 + threadIdx.x;   // 12288 = 2 * 8*3*256
  int branch = gid / 6144;
  int r = gid % 6144;
  int d = r & 255;
  int ock = r >> 8;            // oc*3+k
  int oc = ock / 3, k = ock % 3;
  const float* Wp = branch ? Wp_c : Wp_w;
  const float* C  = branch ? C_c  : C_w;
  float acc = 0.f;
  for (int i = 0; i < ND; ++i) acc += C[(oc*ND + i)*3 + k] * Wp[i*ND + d];
  (branch ? Ec : Ew)[r] = acc;
  if (d == 0){
    const float* bp = branch ? bp_c : bp_w;
    float bb = 0.f;
    for (int i = 0; i < ND; ++i) bb += C[(oc*ND + i)*3 + k] * bp[i];
    (branch ? bc2 : bw2)[ock] = bb;
  }
}

// ------ K3: phoneme (b,d,l) -> phT fp32 (b,l,d) + phTb bf16 (b,l[256pad],d) ----
__global__ void k_transpose(const float* __restrict__ ph, float* __restrict__ phT,
                            ushort_t* __restrict__ phTb)
{
  __shared__ float tile[32][33];
  int b = blockIdx.z;
  int l0 = blockIdx.x*32, d0 = blockIdx.y*32;   // grid.x = 8 covers l 0..255
  int tx = threadIdx.x, ty = threadIdx.y;  // 32 x 8
  #pragma unroll
  for (int i = 0; i < 4; ++i){
    int d = d0 + ty + i*8, l = l0 + tx;
    tile[ty + i*8][tx] = (l < NL) ? ph[((size_t)b*ND + d)*NL + l] : 0.f;
  }
  __syncthreads();
  #pragma unroll
  for (int i = 0; i < 4; ++i){
    int l = l0 + ty + i*8, d = d0 + tx;
    float v = tile[tx][ty + i*8];
    if (l < NL) phT[((size_t)b*NL + l)*ND + d] = v;
    phTb[((size_t)b*256 + l)*ND + d] = f2bf(v);   // rows >=200 are zeros
  }
}

// ---------------- K4: hw/hc = silu(conv(pointwise(ph))) * pm (float4) ----------
__global__ __launch_bounds__(256) void k_hwc(const float* __restrict__ phT,
    const float* __restrict__ dur,
    const float* __restrict__ Ew, const float* __restrict__ Ec,
    const float* __restrict__ bw2, const float* __restrict__ bc2,
    const float* __restrict__ cbw, const float* __restrict__ cbc,
    float* __restrict__ hw, float* __restrict__ hc)
{
  int gid = blockIdx.x*256 + threadIdx.x;   // 51200 = 16*200*16
  int b = gid / (NL*16);
  int r = gid % (NL*16);
  int l = r >> 4;
  int u = r & 15;
  int branch = u >> 3, oc = u & 7;
  const float* E  = branch ? Ec  : Ew;
  const float* b2 = branch ? bc2 : bw2;
  float val = (branch ? cbc : cbw)[oc];
  #pragma unroll
  for (int k = 0; k < 3; ++k){
    int ll = l + k - 1;
    if (ll < 0 || ll >= NL) continue;      // SAME zero-padding: drop term+bias
    float acc = b2[oc*3 + k];
    const float4* Er = (const float4*)(E + (oc*3 + k)*ND);
    const float4* pr = (const float4*)(phT + ((size_t)b*NL + ll)*ND);
    #pragma unroll 8
    for (int d = 0; d < 64; ++d){
      float4 e = Er[d], p = pr[d];
      acc += e.x*p.x + e.y*p.y + e.z*p.z + e.w*p.w;
    }
    val += acc;
  }
  float pm = (dur[b*NL + l] > 0.5f) ? 1.f : 0.f;
  (branch ? hc : hw)[(b*NL + l)*8 + oc] = silu_f(val) * pm;
}

// ---------------- K4b: t-invariant MLP bases per (b,l) -------------------------
__global__ __launch_bounds__(256) void k_base(
    const float* __restrict__ dur, const float* __restrict__ sk_ws,
    const float* __restrict__ hw, const float* __restrict__ hc,
    const float* __restrict__ Mw, const float* __restrict__ mbw,
    const float* __restrict__ Mc, const float* __restrict__ mbc,
    float4* __restrict__ base)
{
  int gid = blockIdx.x*256 + threadIdx.x;   // 16*256
  int b = gid >> 8, l = gid & 255;
  float4 o0 = make_float4(0,0,0,0);
  float4 o1 = make_float4(0,0,0,0);
  if (l < NL){
    float dl  = dur[b*NL + l];
    float pm  = (dl > 0.5f) ? 1.f : 0.f;
    float skl = sk_ws[b*NL + l];
    float c1[4], c2[2];
    #pragma unroll
    for (int q = 0; q < 4; ++q) c1[q] = mbw[q] + dl*Mw[4 + q] - skl*Mw[q];
    #pragma unroll
    for (int p = 0; p < 2; ++p) c2[p] = mbc[p] + dl*Mc[2 + p] - skl*Mc[p];
    const float* hwp = hw + (b*NL + l)*8;
    const float* hcp = hc + (b*NL + l)*8;
    #pragma unroll
    for (int j = 0; j < 8; ++j){
      #pragma unroll
      for (int q = 0; q < 4; ++q) c1[q] += hwp[j]*Mw[(2 + j)*4 + q];
      #pragma unroll
      for (int p = 0; p < 2; ++p) c2[p] += hcp[j]*Mc[(2 + j)*2 + p];
    }
    o0 = make_float4(c1[0], c1[1], c1[2], c1[3]);
    o1 = make_float4(c2[0], c2[1], pm, 0.f);
  }
  base[(size_t)gid*2 + 0] = o0;
  base[(size_t)gid*2 + 1] = o1;
}

// ---------------- K5: one wave per t: softmax over l, w out, vc ----------------
__global__ __launch_bounds__(256) void k_wsoft2(
    const float4* __restrict__ base,
    const int* __restrict__ fl_ws,
    const float* __restrict__ Mw, const float* __restrict__ Mc,
    const float* __restrict__ Lc, const float* __restrict__ lbc,
    float* __restrict__ wout, ushort_t* __restrict__ wbf,
    float* __restrict__ vc)
{
  int b = blockIdx.y;
  int wave = threadIdx.x >> 6, lane = threadIdx.x & 63;
  int t = blockIdx.x*4 + wave;
  int fl = fl_ws[b];

  if (t >= fl){
    #pragma unroll
    for (int q = 0; q < 4; ++q){
      #pragma unroll
      for (int c = 0; c < 4; ++c){
        int l = c*64 + lane;
        if (l < NL) wout[(((size_t)(b*4 + q))*NT + t)*NL + l] = 0.f;
      }
    }
    return;
  }

  float t1 = (float)(t + 1);
  float tqw[4], tqc[2];
  #pragma unroll
  for (int q = 0; q < 4; ++q) tqw[q] = t1 * Mw[q];
  #pragma unroll
  for (int p = 0; p < 2; ++p) tqc[p] = t1 * Mc[p];

  float z[4][4], cv[4][2], msk[4];
  float m[4] = {-INFINITY, -INFINITY, -INFINITY, -INFINITY};
  #pragma unroll
  for (int c = 0; c < 4; ++c){
    int l = c*64 + lane;
    float4 b0 = base[((size_t)(b*256 + l))*2 + 0];
    float4 b1 = base[((size_t)(b*256 + l))*2 + 1];
    float pm = b1.z;
    msk[c] = pm;
    float zz[4] = { b0.x + tqw[0], b0.y + tqw[1], b0.z + tqw[2], b0.w + tqw[3] };
    #pragma unroll
    for (int q = 0; q < 4; ++q){
      float s = silu_f(zz[q]);
      z[c][q] = (pm > 0.f) ? s : -INFINITY;
      m[q] = fmaxf(m[q], z[c][q]);
    }
    cv[c][0] = silu_f(b1.x + tqc[0]);
    cv[c][1] = silu_f(b1.y + tqc[1]);
  }
  #pragma unroll
  for (int q = 0; q < 4; ++q){
    float v = m[q];
    #pragma unroll
    for (int off = 32; off; off >>= 1) v = fmaxf(v, __shfl_xor(v, off));
    m[q] = v;
  }
  float s4[4] = {0,0,0,0};
  #pragma unroll
  for (int c = 0; c < 4; ++c){
    #pragma unroll
    for (int q = 0; q < 4; ++q){
      float e = (msk[c] > 0.f) ? expf(z[c][q] - m[q]) : 0.f;
      z[c][q] = e;
      s4[q] += e;
    }
  }
  #pragma unroll
  for (int q = 0; q < 4; ++q){
    float v = s4[q];
    #pragma unroll
    for (int off = 32; off; off >>= 1) v += __shfl_xor(v, off);
    s4[q] = 1.f / v;
  }
  float wc[8] = {0,0,0,0,0,0,0,0};
  #pragma unroll
  for (int c = 0; c < 4; ++c){
    int l = c*64 + lane;
    bool lv = l < NL;
    #pragma unroll
    for (int q = 0; q < 4; ++q){
      float wq = z[c][q] * s4[q];
      if (lv){
        wout[(((size_t)(b*4 + q))*NT + t)*NL + l] = wq;
        wbf[((size_t)(b*1024 + t))*800 + q*200 + l] = f2bf(wq);
      }
      wc[q*2 + 0] += wq * cv[c][0];
      wc[q*2 + 1] += wq * cv[c][1];
    }
  }
  #pragma unroll
  for (int u = 0; u < 8; ++u){
    float v = wc[u];
    #pragma unroll
    for (int off = 32; off; off >>= 1) v += __shfl_xor(v, off);
    wc[u] = v;
  }
  #pragma unroll
  for (int c = 0; c < 4; ++c){
    int d = c*64 + lane;
    float v = lbc[d];
    #pragma unroll
    for (int u = 0; u < 8; ++u) v += wc[u] * Lc[u*ND + d];
    vc[((size_t)b*NT + t)*ND + d] = v;
  }
}

// ---------------- K6: pack WoT[n][k]=bf16(Wo[k][n]); LwT[q][n][d]=bf16(Lw) -----
__global__ __launch_bounds__(256) void k_packW(const float* __restrict__ Wo,
    const float* __restrict__ Lw,
    ushort_t* __restrict__ WoT, ushort_t* __restrict__ LwT)
{
  int gid = blockIdx.x*256 + threadIdx.x;   // 393216
  if (gid < 131072){
    int n = gid >> 8, k = gid & 255;
    WoT[gid] = f2bf(Wo[(size_t)k*512 + n]);
  } else {
    int r = gid - 131072;        // q*65536 + n*256 + d
    int d = r & 255;
    int qn = r >> 8;
    int q = qn >> 8, n = qn & 255;
    LwT[r] = f2bf(Lw[((size_t)q*256 + d)*256 + n]);
  }
}

// ------- K6c: MFMA Gt[b][n][q*200+l] = sum_d LwT[q][n][d] * phTb[b][l][d] ------
// A-rows = n (LwT), B-rows = l (phTb, padded to 256 with zeros). K = 256.
__global__ __launch_bounds__(256) void k_gemmG_mfma(
    const ushort_t* __restrict__ LwT,   // [4][256][256] bf16
    const ushort_t* __restrict__ phTb,  // [16][256][256] bf16
    ushort_t* __restrict__ Gt)          // [16][256][800] bf16
{
  __shared__ ushort_t As[4096];
  __shared__ ushort_t Bs[4096];
  int bq = blockIdx.z; int b = bq >> 2, q = bq & 3;
  int m0 = blockIdx.y * 128;            // n dim (256 -> 2 tiles)
  int n0 = blockIdx.x * 128;            // l dim (200 -> 2 tiles padded)
  int tid = threadIdx.x, lane = tid & 63, wave = tid >> 6;
  int wm = wave >> 1, wn = wave & 1;
  int col = lane & 15, kg4 = lane >> 4;

  f32x4 acc[4][4] = {};

  for (int kt = 0; kt < 8; ++kt){
    int k0 = kt*32;
    #pragma unroll
    for (int r = 0; r < 2; ++r){
      int o = wave*1024 + r*4096;
      int co = o + (lane << 4);
      int kg = co >> 11, row = (co >> 4) & 127;
      const ushort_t* ga = LwT + ((size_t)(q*256 + m0 + row))*256 + k0 + kg*8;
      __builtin_amdgcn_global_load_lds(GLB_AS(ga), LDS_AS(As + (o >> 1)), 16, 0, 0);
      const ushort_t* gb = phTb + ((size_t)(b*256 + n0 + row))*256 + k0 + kg*8;
      __builtin_amdgcn_global_load_lds(GLB_AS(gb), LDS_AS(Bs + (o >> 1)), 16, 0, 0);
    }
    __builtin_amdgcn_s_waitcnt(0);
    __syncthreads();
    const bf16x8* Av = (const bf16x8*)As;
    const bf16x8* Bv = (const bf16x8*)Bs;
    bf16x8 afr[4], bfr[4];
    #pragma unroll
    for (int i = 0; i < 4; ++i) afr[i] = Av[kg4*128 + wm*64 + i*16 + col];
    #pragma unroll
    for (int j = 0; j < 4; ++j) bfr[j] = Bv[kg4*128 + wn*64 + j*16 + col];
    #pragma unroll
    for (int i = 0; i < 4; ++i)
      #pragma unroll
      for (int j = 0; j < 4; ++j)
        acc[i][j] = __builtin_amdgcn_mfma_f32_16x16x32_bf16(afr[i], bfr[j], acc[i][j], 0, 0, 0);
    __syncthreads();
  }

  int rq = lane >> 4;
  #pragma unroll
  for (int i = 0; i < 4; ++i){
    #pragma unroll
    for (int r = 0; r < 4; ++r){
      int n = m0 + wm*64 + i*16 + rq*4 + r;
      #pragma unroll
      for (int j = 0; j < 4; ++j){
        int l = n0 + wn*64 + j*16 + col;
        if (l < NL)
          Gt[((size_t)b*ND + n)*800 + q*NL + l] = f2bf(acc[i][j][r]);
      }
    }
  }
}

// ------- K7: MFMA vh = w_bf16 @ Gt^T per b; whc = fm*(vh+lbw+vc) -> bf16 -------
__global__ __launch_bounds__(256) void k_gemmV_mfma(
    const ushort_t* __restrict__ wbf,   // [16][1024][800] bf16
    const ushort_t* __restrict__ Gt,    // [16][256][800] bf16
    const float* __restrict__ vc,       // [16][1000][256]
    const float* __restrict__ lbw,      // [256]
    const float* __restrict__ fmv,      // [16][1000]
    ushort_t* __restrict__ whc)         // [16000][256] bf16
{
  __shared__ ushort_t As[4096];   // 8KB: [kg][m][8bf16]
  __shared__ ushort_t Bs[4096];   // 8KB: [kg][n][8bf16]
  int b = blockIdx.z;
  int m0 = blockIdx.y * 128;
  int n0 = blockIdx.x * 128;
  int tid = threadIdx.x, lane = tid & 63, wave = tid >> 6;
  int wm = wave >> 1, wn = wave & 1;
  int col = lane & 15, kg4 = lane >> 4;

  f32x4 acc[4][4] = {};

  for (int kt = 0; kt < 25; ++kt){
    int k0 = kt*32;
    #pragma unroll
    for (int r = 0; r < 2; ++r){
      int o = wave*1024 + r*4096;           // byte offset of this wave's chunk
      int co = o + (lane << 4);
      int kg = co >> 11, row = (co >> 4) & 127;
      const ushort_t* ga = wbf + ((size_t)(b*1024 + m0 + row))*800 + k0 + kg*8;
      __builtin_amdgcn_global_load_lds(GLB_AS(ga), LDS_AS(As + (o >> 1)), 16, 0, 0);
      const ushort_t* gb = Gt + ((size_t)(b*ND + n0 + row))*800 + k0 + kg*8;
      __builtin_amdgcn_global_load_lds(GLB_AS(gb), LDS_AS(Bs + (o >> 1)), 16, 0, 0);
    }
    __builtin_amdgcn_s_waitcnt(0);
    __syncthreads();
    const bf16x8* Av = (const bf16x8*)As;
    const bf16x8* Bv = (const bf16x8*)Bs;
    bf16x8 afr[4], bfr[4];
    #pragma unroll
    for (int i = 0; i < 4; ++i) afr[i] = Av[kg4*128 + wm*64 + i*16 + col];
    #pragma unroll
    for (int j = 0; j < 4; ++j) bfr[j] = Bv[kg4*128 + wn*64 + j*16 + col];
    #pragma unroll
    for (int i = 0; i < 4; ++i)
      #pragma unroll
      for (int j = 0; j < 4; ++j)
        acc[i][j] = __builtin_amdgcn_mfma_f32_16x16x32_bf16(afr[i], bfr[j], acc[i][j], 0, 0, 0);
    __syncthreads();
  }

  int rq = lane >> 4;
  #pragma unroll
  for (int i = 0; i < 4; ++i){
    #pragma unroll
    for (int r = 0; r < 4; ++r){
      int t = m0 + wm*64 + i*16 + rq*4 + r;
      if (t >= NT) continue;
      float f = fmv[b*NT + t];
      #pragma unroll
      for (int j = 0; j < 4; ++j){
        int n = n0 + wn*64 + j*16 + col;
        size_t idx = ((size_t)b*NT + t)*ND + n;
        float v = f * (acc[i][j][r] + lbw[n] + vc[idx]);
        whc[idx] = f2bf(v);
      }
    }
  }
}

// ------- K8: MFMA out = whc_bf16 @ WoT^T + bo, stored transposed (b,s,t) -------
__global__ __launch_bounds__(256) void k_gemmO_mfma(
    const ushort_t* __restrict__ whc,   // [16000][256] bf16
    const ushort_t* __restrict__ WoT,   // [512][256] bf16
    const float* __restrict__ bo,       // [512]
    float* __restrict__ o_mean, float* __restrict__ o_lstd)
{
  __shared__ ushort_t As[4096];
  __shared__ ushort_t Bs[4096];
  int m0 = blockIdx.y * 128;            // over 16000 (125 tiles, exact)
  int n0 = blockIdx.x * 128;            // over 512 (4 tiles)
  int tid = threadIdx.x, lane = tid & 63, wave = tid >> 6;
  int wm = wave >> 1, wn = wave & 1;
  int col = lane & 15, kg4 = lane >> 4;

  f32x4 acc[4][4] = {};

  for (int kt = 0; kt < 8; ++kt){
    int k0 = kt*32;
    #pragma unroll
    for (int r = 0; r < 2; ++r){
      int o = wave*1024 + r*4096;
      int co = o + (lane << 4);
      int kg = co >> 11, row = (co >> 4) & 127;
      const ushort_t* ga = whc + ((size_t)(m0 + row))*ND + k0 + kg*8;
      __builtin_amdgcn_global_load_lds(GLB_AS(ga), LDS_AS(As + (o >> 1)), 16, 0, 0);
      const ushort_t* gb = WoT + ((size_t)(n0 + row))*ND + k0 + kg*8;
      __builtin_amdgcn_global_load_lds(GLB_AS(gb), LDS_AS(Bs + (o >> 1)), 16, 0, 0);
    }
    __builtin_amdgcn_s_waitcnt(0);
    __syncthreads();
    const bf16x8* Av = (const bf16x8*)As;
    const bf16x8* Bv = (const bf16x8*)Bs;
    bf16x8 afr[4], bfr[4];
    #pragma unroll
    for (int i = 0; i < 4; ++i) afr[i] = Av[kg4*128 + wm*64 + i*16 + col];
    #pragma unroll
    for (int j = 0; j < 4; ++j) bfr[j] = Bv[kg4*128 + wn*64 + j*16 + col];
    #pragma unroll
    for (int i = 0; i < 4; ++i)
      #pragma unroll
      for (int j = 0; j < 4; ++j)
        acc[i][j] = __builtin_amdgcn_mfma_f32_16x16x32_bf16(afr[i], bfr[j], acc[i][j], 0, 0, 0);
    __syncthreads();
  }

  int rq = lane >> 4;
  #pragma unroll
  for (int i = 0; i < 4; ++i){
    #pragma unroll
    for (int r = 0; r < 4; ++r){
      int m = m0 + wm*64 + i*16 + rq*4 + r;
      int b = m / NT, t = m - b*NT;
      #pragma unroll
      for (int j = 0; j < 4; ++j){
        int s = n0 + wn*64 + j*16 + col;
        float v = acc[i][j][r] + bo[s];
        if (s < ND) o_mean[((size_t)b*ND + s)*NT + t] = v;
        else        o_lstd[((size_t)b*ND + (s - ND))*NT + t] = v;
      }
    }
  }
}

extern "C" void kernel_launch(void* const* d_in, const int* in_sizes, int n_in,
                              void* d_out, int out_size, void* d_ws, size_t ws_size,
                              hipStream_t stream)
{
  const float* dur = (const float*)d_in[0];
  const float* ph  = (const float*)d_in[1];
  // d_in[2] phoneme_mask: unused (pm == durations > 0)
  const float* Wpw = (const float*)d_in[3];
  const float* bpw = (const float*)d_in[4];
  const float* Cw  = (const float*)d_in[5];
  const float* cbw = (const float*)d_in[6];
  const float* Mw  = (const float*)d_in[7];
  const float* mbw = (const float*)d_in[8];
  const float* Lw  = (const float*)d_in[9];
  const float* lbw = (const float*)d_in[10];
  const float* Wpc = (const float*)d_in[11];
  const float* bpc = (const float*)d_in[12];
  const float* Cc  = (const float*)d_in[13];
  const float* cbc = (const float*)d_in[14];
  const float* Mc  = (const float*)d_in[15];
  const float* mbc = (const float*)d_in[16];
  const float* Lc  = (const float*)d_in[17];
  const float* lbc = (const float*)d_in[18];
  const float* Wo  = (const float*)d_in[19];
  const float* bo  = (const float*)d_in[20];

  float* out    = (float*)d_out;
  float* o_mean = out;
  float* o_lstd = out + (size_t)NB*ND*NT;
  float* o_fm   = o_lstd + (size_t)NB*ND*NT;
  float* o_fl   = o_fm + NB*NT;
  float* o_w    = o_fl + NB;

  float* ws   = (float*)d_ws;
  float* phT  = ws + OFF_PHT;
  float* vc   = ws + OFF_VC;
  float* hw   = ws + OFF_HW;
  float* hc   = ws + OFF_HC;
  float* sk   = ws + OFF_SK;
  float* Ew   = ws + OFF_EW;
  float* Ec   = ws + OFF_EC;
  float* bw2  = ws + OFF_BW2;
  float* bc2  = ws + OFF_BC2;
  int*   fl   = (int*)(ws + OFF_FL);
  ushort_t* wbf  = (ushort_t*)(ws + OFF_WBF);
  ushort_t* Gt   = (ushort_t*)(ws + OFF_GT);
  ushort_t* whc  = (ushort_t*)(ws + OFF_WHC);
  ushort_t* WoT  = (ushort_t*)(ws + OFF_WOT);
  float4*   base = (float4*)(ws + OFF_BASE);
  ushort_t* phTb = (ushort_t*)(ws + OFF_PHTB);
  ushort_t* LwT  = (ushort_t*)(ws + OFF_LWT);

  k_prep<<<NB, 256, 0, stream>>>(dur, sk, fl, o_fm, o_fl);
  k_combine<<<48, 256, 0, stream>>>(Wpw, Cw, bpw, Wpc, Cc, bpc, Ew, Ec, bw2, bc2);
  {
    dim3 g(8, 8, NB), blk(32, 8);
    k_transpose<<<g, blk, 0, stream>>>(ph, phT, phTb);
  }
  k_hwc<<<200, 256, 0, stream>>>(phT, dur, Ew, Ec, bw2, bc2, cbw, cbc, hw, hc);
  k_packW<<<1536, 256, 0, stream>>>(Wo, Lw, WoT, LwT);
  k_base<<<16, 256, 0, stream>>>(dur, sk, hw, hc, Mw, mbw, Mc, mbc, base);
  {
    dim3 g(250, NB);
    k_wsoft2<<<g, 256, 0, stream>>>(base, fl, Mw, Mc, Lc, lbc, o_w, wbf, vc);
  }
  {
    dim3 g(2, 2, NB*4);
    k_gemmG_mfma<<<g, 256, 0, stream>>>(LwT, phTb, Gt);
  }
  {
    dim3 g(2, 8, NB);
    k_gemmV_mfma<<<g, 256, 0, stream>>>(wbf, Gt, vc, lbw, o_fm, whc);
  }
  {
    dim3 g(4, 125);
    k_gemmO_mfma<<<g, 256, 0, stream>>>(whc, WoT, bo, o_mean, o_lstd);
  }
}

// Round 5
// 268.725 us; speedup vs baseline: 1.6593x; 1.0991x over previous
//
#include <hip/hip_runtime.h>
#include <hip/hip_bf16.h>
#include <math.h>

#define NB 16
#define ND 256
#define NL 200
#define NT 1000

typedef unsigned short ushort_t;
typedef __bf16 bf16x8 __attribute__((ext_vector_type(8)));
typedef float f32x4 __attribute__((ext_vector_type(4)));

#define LDS_AS(p) ((__attribute__((address_space(3))) void*)(p))
#define GLB_AS(p) ((const __attribute__((address_space(1))) void*)(p))

// ---- workspace layout (float offsets) ----
#define OFF_PHT   0u         // phT[b][l][d] fp32            819200
#define OFF_WC8   819200u    // wc8[b][1000][8] fp32         128000
#define OFF_SK    4966400u   // exclusive cumsum             3200
#define OFF_EW    4969600u   // E[oc][k][d]                  6144
#define OFF_EC    4975744u   //                              6144
#define OFF_BW2   4981888u   //                              24
#define OFF_BC2   4981912u   //                              24
#define OFF_FL    4981936u   // frame_lengths int            16
#define OFF_WBF   4981952u   // w bf16 [b][1024][800]        6553600 floats
#define OFF_GT    11535552u  // Gt bf16 [b][256][800]        1638400 floats
#define OFF_WHC   13173952u  // whc bf16 [16000][256]        2048000 floats
#define OFF_WOT   15221952u  // WoT bf16 [512][256]          65536 floats
#define OFF_BASE  15287488u  // base[b][256][8] fp32         32768 floats
#define OFF_PHTB  15320256u  // phTb bf16 [b][256pad][256]   524288 floats
#define OFF_LWT   15844544u  // LwT bf16 [4][256][256]       131072 floats

__device__ __forceinline__ float silu_f(float x){ return x / (1.f + __expf(-x)); }
__device__ __forceinline__ ushort_t f2bf(float x){
  __hip_bfloat16 h = __float2bfloat16(x);
  return *(ushort_t*)&h;
}

// ---------------- K1: durations -> sk, frame_lengths, frame_mask ----------------
__global__ __launch_bounds__(256) void k_prep(const float* __restrict__ dur,
    float* __restrict__ sk_ws, int* __restrict__ fl_ws,
    float* __restrict__ o_fm, float* __restrict__ o_fl)
{
  int b = blockIdx.x, tid = threadIdx.x;
  __shared__ float sdur[NL];
  __shared__ float ssk[NL];
  __shared__ int sfl;
  if (tid < NL) sdur[tid] = dur[b*NL + tid];
  __syncthreads();
  if (tid == 0){
    float run = 0.f;
    for (int l = 0; l < NL; ++l){ ssk[l] = run; run += sdur[l]; }
    int fl = (int)rintf(run);            // round-half-even, matches jnp.round
    fl = fl < 0 ? 0 : (fl > NT ? NT : fl);
    sfl = fl; fl_ws[b] = fl; o_fl[b] = (float)fl;
  }
  __syncthreads();
  if (tid < NL) sk_ws[b*NL + tid] = ssk[tid];
  for (int t = tid; t < NT; t += 256) o_fm[b*NT + t] = (t < sfl) ? 1.f : 0.f;
}

// ------ K2: merged param prep: conv-fold E/bias2 + WoT/LwT bf16 packs ----------
__global__ __launch_bounds__(256) void k_setup(
    const float* __restrict__ Wp_w, const float* __restrict__ C_w, const float* __restrict__ bp_w,
    const float* __restrict__ Wp_c, const float* __restrict__ C_c, const float* __restrict__ bp_c,
    const float* __restrict__ Wo, const float* __restrict__ Lw,
    float* __restrict__ Ew, float* __restrict__ Ec,
    float* __restrict__ bw2, float* __restrict__ bc2,
    ushort_t* __restrict__ WoT, ushort_t* __restrict__ LwT)
{
  int bid = blockIdx.x;
  if (bid < 48){
    int gid = bid*256 + threadIdx.x;   // 12288 = 2 * 8*3*256
    int branch = gid / 6144;
    int r = gid % 6144;
    int d = r & 255;
    int ock = r >> 8;            // oc*3+k
    int oc = ock / 3, k = ock % 3;
    const float* Wp = branch ? Wp_c : Wp_w;
    const float* C  = branch ? C_c  : C_w;
    float acc = 0.f;
    for (int i = 0; i < ND; ++i) acc += C[(oc*ND + i)*3 + k] * Wp[i*ND + d];
    (branch ? Ec : Ew)[r] = acc;
    if (d == 0){
      const float* bp = branch ? bp_c : bp_w;
      float bb = 0.f;
      for (int i = 0; i < ND; ++i) bb += C[(oc*ND + i)*3 + k] * bp[i];
      (branch ? bc2 : bw2)[ock] = bb;
    }
  } else {
    int gid = (bid - 48)*256 + threadIdx.x;   // 393216
    if (gid < 131072){
      int n = gid >> 8, k = gid & 255;
      WoT[gid] = f2bf(Wo[(size_t)k*512 + n]);
    } else {
      int r = gid - 131072;        // q*65536 + n*256 + d
      int d = r & 255;
      int qn = r >> 8;
      int q = qn >> 8, n = qn & 255;
      LwT[r] = f2bf(Lw[((size_t)q*256 + d)*256 + n]);
    }
  }
}

// ------ K3: phoneme (b,d,l) -> phT fp32 (b,l,d) + phTb bf16 (b,l[256pad],d) ----
__global__ void k_transpose(const float* __restrict__ ph, float* __restrict__ phT,
                            ushort_t* __restrict__ phTb)
{
  __shared__ float tile[32][33];
  int b = blockIdx.z;
  int l0 = blockIdx.x*32, d0 = blockIdx.y*32;   // grid.x = 8 covers l 0..255
  int tx = threadIdx.x, ty = threadIdx.y;  // 32 x 8
  #pragma unroll
  for (int i = 0; i < 4; ++i){
    int d = d0 + ty + i*8, l = l0 + tx;
    tile[ty + i*8][tx] = (l < NL) ? ph[((size_t)b*ND + d)*NL + l] : 0.f;
  }
  __syncthreads();
  #pragma unroll
  for (int i = 0; i < 4; ++i){
    int l = l0 + ty + i*8, d = d0 + tx;
    float v = tile[tx][ty + i*8];
    if (l < NL) phT[((size_t)b*NL + l)*ND + d] = v;
    phTb[((size_t)b*256 + l)*ND + d] = f2bf(v);   // rows >=200 are zeros
  }
}

// ------ K4: fused conv-swish h + t-invariant MLP bases per (b,l) ---------------
// grid (16, NB): x<13 compute 16 l's each; x>=13 zero-fill base rows 208..255.
__global__ __launch_bounds__(256) void k_hwc2(const float* __restrict__ phT,
    const float* __restrict__ dur, const float* __restrict__ sk_ws,
    const float* __restrict__ Ew, const float* __restrict__ Ec,
    const float* __restrict__ bw2, const float* __restrict__ bc2,
    const float* __restrict__ cbw, const float* __restrict__ cbc,
    const float* __restrict__ Mw, const float* __restrict__ mbw,
    const float* __restrict__ Mc, const float* __restrict__ mbc,
    float4* __restrict__ base)
{
  int b = blockIdx.y, x = blockIdx.x, tid = threadIdx.x;
  if (x >= 13){
    int l0 = 208 + (x - 13)*16;
    if (tid < 32)
      base[((size_t)(b*256 + l0 + (tid >> 1)))*2 + (tid & 1)] = make_float4(0,0,0,0);
    return;
  }
  __shared__ float sh[16][17];
  int lu = tid >> 4, u = tid & 15;
  int l = x*16 + lu;
  float h = 0.f;
  if (l < NL){
    int branch = u >> 3, oc = u & 7;
    const float* E  = branch ? Ec  : Ew;
    const float* b2 = branch ? bc2 : bw2;
    float val = (branch ? cbc : cbw)[oc];
    #pragma unroll
    for (int k = 0; k < 3; ++k){
      int ll = l + k - 1;
      if (ll < 0 || ll >= NL) continue;      // SAME zero-padding: drop term+bias
      float acc = b2[oc*3 + k];
      const float4* Er = (const float4*)(E + (oc*3 + k)*ND);
      const float4* pr = (const float4*)(phT + ((size_t)b*NL + ll)*ND);
      #pragma unroll 8
      for (int d = 0; d < 64; ++d){
        float4 e = Er[d], p = pr[d];
        acc += e.x*p.x + e.y*p.y + e.z*p.z + e.w*p.w;
      }
      val += acc;
    }
    float pm = (dur[b*NL + l] > 0.5f) ? 1.f : 0.f;
    h = silu_f(val) * pm;
  }
  sh[lu][u] = h;
  __syncthreads();
  if (tid < 16){
    int ll = x*16 + tid;
    float4 o0 = make_float4(0,0,0,0);
    float4 o1 = make_float4(0,0,0,0);
    if (ll < NL){
      float dl  = dur[b*NL + ll];
      float pm  = (dl > 0.5f) ? 1.f : 0.f;
      float skl = sk_ws[b*NL + ll];
      float c1[4], c2[2];
      #pragma unroll
      for (int q = 0; q < 4; ++q) c1[q] = mbw[q] + dl*Mw[4 + q] - skl*Mw[q];
      #pragma unroll
      for (int p = 0; p < 2; ++p) c2[p] = mbc[p] + dl*Mc[2 + p] - skl*Mc[p];
      #pragma unroll
      for (int j = 0; j < 8; ++j){
        float hwv = sh[tid][j], hcv = sh[tid][8 + j];
        #pragma unroll
        for (int q = 0; q < 4; ++q) c1[q] += hwv*Mw[(2 + j)*4 + q];
        #pragma unroll
        for (int p = 0; p < 2; ++p) c2[p] += hcv*Mc[(2 + j)*2 + p];
      }
      o0 = make_float4(c1[0], c1[1], c1[2], c1[3]);
      o1 = make_float4(c2[0], c2[1], pm, 0.f);
    }
    base[((size_t)(b*256 + ll))*2 + 0] = o0;
    base[((size_t)(b*256 + ll))*2 + 1] = o1;
  }
}

// ---------------- K5: one wave per t: softmax over l, w out, wc8 ---------------
__global__ __launch_bounds__(256) void k_wsoft2(
    const float4* __restrict__ base,
    const int* __restrict__ fl_ws,
    const float* __restrict__ Mw, const float* __restrict__ Mc,
    float* __restrict__ wout, ushort_t* __restrict__ wbf,
    float* __restrict__ wc8)
{
  int b = blockIdx.y;
  int wave = threadIdx.x >> 6, lane = threadIdx.x & 63;
  int t = blockIdx.x*4 + wave;
  int fl = fl_ws[b];

  if (t >= fl){
    #pragma unroll
    for (int q = 0; q < 4; ++q){
      #pragma unroll
      for (int c = 0; c < 4; ++c){
        int l = c*64 + lane;
        if (l < NL) wout[(((size_t)(b*4 + q))*NT + t)*NL + l] = 0.f;
      }
    }
    if (lane == 0){
      float4* wp = (float4*)(wc8 + ((size_t)b*NT + t)*8);
      wp[0] = make_float4(0,0,0,0);
      wp[1] = make_float4(0,0,0,0);
    }
    return;
  }

  float t1 = (float)(t + 1);
  float tqw[4], tqc[2];
  #pragma unroll
  for (int q = 0; q < 4; ++q) tqw[q] = t1 * Mw[q];
  #pragma unroll
  for (int p = 0; p < 2; ++p) tqc[p] = t1 * Mc[p];

  float z[4][4], cv[4][2], msk[4];
  float m[4] = {-INFINITY, -INFINITY, -INFINITY, -INFINITY};
  #pragma unroll
  for (int c = 0; c < 4; ++c){
    int l = c*64 + lane;
    float4 b0 = base[((size_t)(b*256 + l))*2 + 0];
    float4 b1 = base[((size_t)(b*256 + l))*2 + 1];
    float pm = b1.z;
    msk[c] = pm;
    float zz[4] = { b0.x + tqw[0], b0.y + tqw[1], b0.z + tqw[2], b0.w + tqw[3] };
    #pragma unroll
    for (int q = 0; q < 4; ++q){
      float s = silu_f(zz[q]);
      z[c][q] = (pm > 0.f) ? s : -INFINITY;
      m[q] = fmaxf(m[q], z[c][q]);
    }
    cv[c][0] = silu_f(b1.x + tqc[0]);
    cv[c][1] = silu_f(b1.y + tqc[1]);
  }
  #pragma unroll
  for (int q = 0; q < 4; ++q){
    float v = m[q];
    #pragma unroll
    for (int off = 32; off; off >>= 1) v = fmaxf(v, __shfl_xor(v, off));
    m[q] = v;
  }
  float s4[4] = {0,0,0,0};
  #pragma unroll
  for (int c = 0; c < 4; ++c){
    #pragma unroll
    for (int q = 0; q < 4; ++q){
      float e = (msk[c] > 0.f) ? __expf(z[c][q] - m[q]) : 0.f;
      z[c][q] = e;
      s4[q] += e;
    }
  }
  #pragma unroll
  for (int q = 0; q < 4; ++q){
    float v = s4[q];
    #pragma unroll
    for (int off = 32; off; off >>= 1) v += __shfl_xor(v, off);
    s4[q] = 1.f / v;
  }
  float wc[8] = {0,0,0,0,0,0,0,0};
  #pragma unroll
  for (int c = 0; c < 4; ++c){
    int l = c*64 + lane;
    bool lv = l < NL;
    #pragma unroll
    for (int q = 0; q < 4; ++q){
      float wq = z[c][q] * s4[q];
      if (lv){
        wout[(((size_t)(b*4 + q))*NT + t)*NL + l] = wq;
        wbf[((size_t)(b*1024 + t))*800 + q*200 + l] = f2bf(wq);
      }
      wc[q*2 + 0] += wq * cv[c][0];
      wc[q*2 + 1] += wq * cv[c][1];
    }
  }
  #pragma unroll
  for (int u = 0; u < 8; ++u){
    float v = wc[u];
    #pragma unroll
    for (int off = 32; off; off >>= 1) v += __shfl_xor(v, off);
    wc[u] = v;
  }
  if (lane == 0){
    float4* wp = (float4*)(wc8 + ((size_t)b*NT + t)*8);
    wp[0] = make_float4(wc[0], wc[1], wc[2], wc[3]);
    wp[1] = make_float4(wc[4], wc[5], wc[6], wc[7]);
  }
}

// ------- K6: MFMA Gt[b][n][q*200+l] = sum_d LwT[q][n][d] * phTb[b][l][d] -------
__global__ __launch_bounds__(256) void k_gemmG_mfma(
    const ushort_t* __restrict__ LwT,   // [4][256][256] bf16
    const ushort_t* __restrict__ phTb,  // [16][256][256] bf16
    ushort_t* __restrict__ Gt)          // [16][256][800] bf16
{
  __shared__ ushort_t As[4096];
  __shared__ ushort_t Bs[4096];
  int bq = blockIdx.z; int b = bq >> 2, q = bq & 3;
  int m0 = blockIdx.y * 128;            // n dim (256 -> 2 tiles)
  int n0 = blockIdx.x * 128;            // l dim (200 -> 2 tiles padded)
  int tid = threadIdx.x, lane = tid & 63, wave = tid >> 6;
  int wm = wave >> 1, wn = wave & 1;
  int col = lane & 15, kg4 = lane >> 4;

  f32x4 acc[4][4] = {};

  for (int kt = 0; kt < 8; ++kt){
    int k0 = kt*32;
    #pragma unroll
    for (int r = 0; r < 2; ++r){
      int o = wave*1024 + r*4096;
      int co = o + (lane << 4);
      int kg = co >> 11, row = (co >> 4) & 127;
      const ushort_t* ga = LwT + ((size_t)(q*256 + m0 + row))*256 + k0 + kg*8;
      __builtin_amdgcn_global_load_lds(GLB_AS(ga), LDS_AS(As + (o >> 1)), 16, 0, 0);
      const ushort_t* gb = phTb + ((size_t)(b*256 + n0 + row))*256 + k0 + kg*8;
      __builtin_amdgcn_global_load_lds(GLB_AS(gb), LDS_AS(Bs + (o >> 1)), 16, 0, 0);
    }
    __builtin_amdgcn_s_waitcnt(0);
    __syncthreads();
    const bf16x8* Av = (const bf16x8*)As;
    const bf16x8* Bv = (const bf16x8*)Bs;
    bf16x8 afr[4], bfr[4];
    #pragma unroll
    for (int i = 0; i < 4; ++i) afr[i] = Av[kg4*128 + wm*64 + i*16 + col];
    #pragma unroll
    for (int j = 0; j < 4; ++j) bfr[j] = Bv[kg4*128 + wn*64 + j*16 + col];
    #pragma unroll
    for (int i = 0; i < 4; ++i)
      #pragma unroll
      for (int j = 0; j < 4; ++j)
        acc[i][j] = __builtin_amdgcn_mfma_f32_16x16x32_bf16(afr[i], bfr[j], acc[i][j], 0, 0, 0);
    __syncthreads();
  }

  int rq = lane >> 4;
  #pragma unroll
  for (int i = 0; i < 4; ++i){
    #pragma unroll
    for (int r = 0; r < 4; ++r){
      int n = m0 + wm*64 + i*16 + rq*4 + r;
      #pragma unroll
      for (int j = 0; j < 4; ++j){
        int l = n0 + wn*64 + j*16 + col;
        if (l < NL)
          Gt[((size_t)b*ND + n)*800 + q*NL + l] = f2bf(acc[i][j][r]);
      }
    }
  }
}

// ------- K7: MFMA vh (64x128 tiles, 2 blk/CU); whc = fm*(vh+lbw+vc(wc8)) -------
__global__ __launch_bounds__(256) void k_gemmV_mfma(
    const ushort_t* __restrict__ wbf,   // [16][1024][800] bf16
    const ushort_t* __restrict__ Gt,    // [16][256][800] bf16
    const float* __restrict__ wc8,      // [16][1000][8]
    const float* __restrict__ Lc,       // [8][256]
    const float* __restrict__ lbc,      // [256]
    const float* __restrict__ lbw,      // [256]
    const float* __restrict__ fmv,      // [16][1000]
    ushort_t* __restrict__ whc)         // [16000][256] bf16
{
  __shared__ ushort_t As[2048];   // 4KB: [kg][m(64)][8bf16]
  __shared__ ushort_t Bs[4096];   // 8KB: [kg][n(128)][8bf16]
  int b = blockIdx.z;
  int m0 = blockIdx.y * 64;       // t (16 tiles over 1024)
  int n0 = blockIdx.x * 128;      // n (2 tiles over 256)
  int tid = threadIdx.x, lane = tid & 63, wave = tid >> 6;
  int col = lane & 15, kg4 = lane >> 4;

  f32x4 acc[4][2] = {};

  for (int kt = 0; kt < 25; ++kt){
    int k0 = kt*32;
    #pragma unroll
    for (int r = 0; r < 3; ++r){
      int o = (wave*3 + r) << 10;        // 12 x 1KB chunks
      int co = o + (lane << 4);
      if (o < 4096){                      // A chunk (wave-uniform test)
        int kg = co >> 10, row = (co >> 4) & 63;
        const ushort_t* ga = wbf + ((size_t)(b*1024 + m0 + row))*800 + k0 + kg*8;
        __builtin_amdgcn_global_load_lds(GLB_AS(ga), LDS_AS(As + (o >> 1)), 16, 0, 0);
      } else {
        int cb = co - 4096;
        int kg = cb >> 11, row = (cb >> 4) & 127;
        const ushort_t* gb = Gt + ((size_t)(b*ND + n0 + row))*800 + k0 + kg*8;
        __builtin_amdgcn_global_load_lds(GLB_AS(gb), LDS_AS(Bs + ((o - 4096) >> 1)), 16, 0, 0);
      }
    }
    __builtin_amdgcn_s_waitcnt(0);
    __syncthreads();
    const bf16x8* Av = (const bf16x8*)As;
    const bf16x8* Bv = (const bf16x8*)Bs;
    bf16x8 afr[4], bfr[2];
    #pragma unroll
    for (int i = 0; i < 4; ++i) afr[i] = Av[kg4*64 + i*16 + col];
    #pragma unroll
    for (int j = 0; j < 2; ++j) bfr[j] = Bv[kg4*128 + wave*32 + j*16 + col];
    #pragma unroll
    for (int i = 0; i < 4; ++i)
      #pragma unroll
      for (int j = 0; j < 2; ++j)
        acc[i][j] = __builtin_amdgcn_mfma_f32_16x16x32_bf16(afr[i], bfr[j], acc[i][j], 0, 0, 0);
    __syncthreads();
  }

  int rq = lane >> 4;
  float lcn[2][8], lbn[2], lbwn[2];
  #pragma unroll
  for (int j = 0; j < 2; ++j){
    int n = n0 + wave*32 + j*16 + col;
    lbn[j] = lbc[n]; lbwn[j] = lbw[n];
    #pragma unroll
    for (int u = 0; u < 8; ++u) lcn[j][u] = Lc[u*ND + n];
  }
  #pragma unroll
  for (int i = 0; i < 4; ++i){
    #pragma unroll
    for (int r = 0; r < 4; ++r){
      int t = m0 + i*16 + rq*4 + r;
      if (t >= NT) continue;
      float f = fmv[b*NT + t];
      const float4* wp = (const float4*)(wc8 + ((size_t)b*NT + t)*8);
      float4 w0 = wp[0], w1 = wp[1];
      #pragma unroll
      for (int j = 0; j < 2; ++j){
        float vcv = lbn[j]
          + w0.x*lcn[j][0] + w0.y*lcn[j][1] + w0.z*lcn[j][2] + w0.w*lcn[j][3]
          + w1.x*lcn[j][4] + w1.y*lcn[j][5] + w1.z*lcn[j][6] + w1.w*lcn[j][7];
        int n = n0 + wave*32 + j*16 + col;
        whc[((size_t)b*NT + t)*ND + n] = f2bf(f * (acc[i][j][r] + lbwn[j] + vcv));
      }
    }
  }
}

// ------- K8: MFMA out = WoT(s-rows) x whc(bt-rows): coalesced t-stores ---------
__global__ __launch_bounds__(256) void k_gemmO_mfma(
    const ushort_t* __restrict__ whc,   // [16000][256] bf16
    const ushort_t* __restrict__ WoT,   // [512][256] bf16
    const float* __restrict__ bo,       // [512]
    float* __restrict__ o_mean, float* __restrict__ o_lstd)
{
  __shared__ ushort_t As[4096];
  __shared__ ushort_t Bs[4096];
  int m0 = blockIdx.y * 128;            // s (4 tiles over 512)
  int n0 = blockIdx.x * 128;            // bt (125 tiles over 16000)
  int tid = threadIdx.x, lane = tid & 63, wave = tid >> 6;
  int wm = wave >> 1, wn = wave & 1;
  int col = lane & 15, kg4 = lane >> 4;

  f32x4 acc[4][4] = {};

  for (int kt = 0; kt < 8; ++kt){
    int k0 = kt*32;
    #pragma unroll
    for (int r = 0; r < 2; ++r){
      int o = wave*1024 + r*4096;
      int co = o + (lane << 4);
      int kg = co >> 11, row = (co >> 4) & 127;
      const ushort_t* ga = WoT + ((size_t)(m0 + row))*ND + k0 + kg*8;
      __builtin_amdgcn_global_load_lds(GLB_AS(ga), LDS_AS(As + (o >> 1)), 16, 0, 0);
      const ushort_t* gb = whc + ((size_t)(n0 + row))*ND + k0 + kg*8;
      __builtin_amdgcn_global_load_lds(GLB_AS(gb), LDS_AS(Bs + (o >> 1)), 16, 0, 0);
    }
    __builtin_amdgcn_s_waitcnt(0);
    __syncthreads();
    const bf16x8* Av = (const bf16x8*)As;
    const bf16x8* Bv = (const bf16x8*)Bs;
    bf16x8 afr[4], bfr[4];
    #pragma unroll
    for (int i = 0; i < 4; ++i) afr[i] = Av[kg4*128 + wm*64 + i*16 + col];
    #pragma unroll
    for (int j = 0; j < 4; ++j) bfr[j] = Bv[kg4*128 + wn*64 + j*16 + col];
    #pragma unroll
    for (int i = 0; i < 4; ++i)
      #pragma unroll
      for (int j = 0; j < 4; ++j)
        acc[i][j] = __builtin_amdgcn_mfma_f32_16x16x32_bf16(afr[i], bfr[j], acc[i][j], 0, 0, 0);
    __syncthreads();
  }

  int rq = lane >> 4;
  #pragma unroll
  for (int i = 0; i < 4; ++i){
    #pragma unroll
    for (int r = 0; r < 4; ++r){
      int s = m0 + wm*64 + i*16 + rq*4 + r;
      float bov = bo[s];
      #pragma unroll
      for (int j = 0; j < 4; ++j){
        int bt = n0 + wn*64 + j*16 + col;
        int b = bt / NT, t = bt - b*NT;
        float v = acc[i][j][r] + bov;
        if (s < ND) o_mean[((size_t)b*ND + s)*NT + t] = v;
        else        o_lstd[((size_t)b*ND + (s - ND))*NT + t] = v;
      }
    }
  }
}

extern "C" void kernel_launch(void* const* d_in, const int* in_sizes, int n_in,
                              void* d_out, int out_size, void* d_ws, size_t ws_size,
                              hipStream_t stream)
{
  const float* dur = (const float*)d_in[0];
  const float* ph  = (const float*)d_in[1];
  // d_in[2] phoneme_mask: unused (pm == durations > 0)
  const float* Wpw = (const float*)d_in[3];
  const float* bpw = (const float*)d_in[4];
  const float* Cw  = (const float*)d_in[5];
  const float* cbw = (const float*)d_in[6];
  const float* Mw  = (const float*)d_in[7];
  const float* mbw = (const float*)d_in[8];
  const float* Lw  = (const float*)d_in[9];
  const float* lbw = (const float*)d_in[10];
  const float* Wpc = (const float*)d_in[11];
  const float* bpc = (const float*)d_in[12];
  const float* Cc  = (const float*)d_in[13];
  const float* cbc = (const float*)d_in[14];
  const float* Mc  = (const float*)d_in[15];
  const float* mbc = (const float*)d_in[16];
  const float* Lc  = (const float*)d_in[17];
  const float* lbc = (const float*)d_in[18];
  const float* Wo  = (const float*)d_in[19];
  const float* bo  = (const float*)d_in[20];

  float* out    = (float*)d_out;
  float* o_mean = out;
  float* o_lstd = out + (size_t)NB*ND*NT;
  float* o_fm   = o_lstd + (size_t)NB*ND*NT;
  float* o_fl   = o_fm + NB*NT;
  float* o_w    = o_fl + NB;

  float* ws   = (float*)d_ws;
  float* phT  = ws + OFF_PHT;
  float* wc8  = ws + OFF_WC8;
  float* sk   = ws + OFF_SK;
  float* Ew   = ws + OFF_EW;
  float* Ec   = ws + OFF_EC;
  float* bw2  = ws + OFF_BW2;
  float* bc2  = ws + OFF_BC2;
  int*   fl   = (int*)(ws + OFF_FL);
  ushort_t* wbf  = (ushort_t*)(ws + OFF_WBF);
  ushort_t* Gt   = (ushort_t*)(ws + OFF_GT);
  ushort_t* whc  = (ushort_t*)(ws + OFF_WHC);
  ushort_t* WoT  = (ushort_t*)(ws + OFF_WOT);
  float4*   base = (float4*)(ws + OFF_BASE);
  ushort_t* phTb = (ushort_t*)(ws + OFF_PHTB);
  ushort_t* LwT  = (ushort_t*)(ws + OFF_LWT);

  k_prep<<<NB, 256, 0, stream>>>(dur, sk, fl, o_fm, o_fl);
  k_setup<<<1584, 256, 0, stream>>>(Wpw, Cw, bpw, Wpc, Cc, bpc, Wo, Lw,
                                    Ew, Ec, bw2, bc2, WoT, LwT);
  {
    dim3 g(8, 8, NB), blk(32, 8);
    k_transpose<<<g, blk, 0, stream>>>(ph, phT, phTb);
  }
  {
    dim3 g(16, NB);
    k_hwc2<<<g, 256, 0, stream>>>(phT, dur, sk, Ew, Ec, bw2, bc2, cbw, cbc,
                                  Mw, mbw, Mc, mbc, base);
  }
  {
    dim3 g(250, NB);
    k_wsoft2<<<g, 256, 0, stream>>>(base, fl, Mw, Mc, o_w, wbf, wc8);
  }
  {
    dim3 g(2, 2, NB*4);
    k_gemmG_mfma<<<g, 256, 0, stream>>>(LwT, phTb, Gt);
  }
  {
    dim3 g(2, 16, NB);
    k_gemmV_mfma<<<g, 256, 0, stream>>>(wbf, Gt, wc8, Lc, lbc, lbw, o_fm, whc);
  }
  {
    dim3 g(125, 4);
    k_gemmO_mfma<<<g, 256, 0, stream>>>(whc, WoT, bo, o_mean, o_lstd);
  }
}

// Round 6
// 266.587 us; speedup vs baseline: 1.6726x; 1.0080x over previous
//
#include <hip/hip_runtime.h>
#include <hip/hip_bf16.h>
#include <math.h>

#define NB 16
#define ND 256
#define NL 200
#define NT 1000

typedef unsigned short ushort_t;
typedef __bf16 bf16x8 __attribute__((ext_vector_type(8)));
typedef float f32x4 __attribute__((ext_vector_type(4)));

#define LDS_AS(p) ((__attribute__((address_space(3))) void*)(p))
#define GLB_AS(p) ((const __attribute__((address_space(1))) void*)(p))

// ---- workspace layout (float offsets) ----
#define OFF_PHT   0u         // phT[b][l][d] fp32            819200
#define OFF_SK    4966400u   // exclusive cumsum             3200
#define OFF_EW    4969600u   // E[oc][k][d]                  6144
#define OFF_EC    4975744u   //                              6144
#define OFF_BW2   4981888u   //                              24
#define OFF_BC2   4981912u   //                              24
#define OFF_FL    4981936u   // frame_lengths int            16
#define OFF_GT    11535552u  // Gt bf16 [b][256][800]        1638400 floats
#define OFF_WHC   13173952u  // whc bf16 [16000][256]        2048000 floats
#define OFF_WOT   15221952u  // WoT bf16 [512][256]          65536 floats
#define OFF_BASE  15287488u  // base[b][256][8] fp32         32768 floats
#define OFF_PHTB  15320256u  // phTb bf16 [b][256pad][256]   524288 floats
#define OFF_LWT   15844544u  // LwT bf16 [4][256][256]       131072 floats

__device__ __forceinline__ float silu_f(float x){ return x / (1.f + __expf(-x)); }
__device__ __forceinline__ ushort_t f2bf(float x){
  __hip_bfloat16 h = __float2bfloat16(x);
  return *(ushort_t*)&h;
}

// ---------------- K1: durations -> sk, frame_lengths, frame_mask ----------------
__global__ __launch_bounds__(256) void k_prep(const float* __restrict__ dur,
    float* __restrict__ sk_ws, int* __restrict__ fl_ws,
    float* __restrict__ o_fm, float* __restrict__ o_fl)
{
  int b = blockIdx.x, tid = threadIdx.x;
  __shared__ float sdur[NL];
  __shared__ float ssk[NL];
  __shared__ int sfl;
  if (tid < NL) sdur[tid] = dur[b*NL + tid];
  __syncthreads();
  if (tid == 0){
    float run = 0.f;
    for (int l = 0; l < NL; ++l){ ssk[l] = run; run += sdur[l]; }
    int fl = (int)rintf(run);            // round-half-even, matches jnp.round
    fl = fl < 0 ? 0 : (fl > NT ? NT : fl);
    sfl = fl; fl_ws[b] = fl; o_fl[b] = (float)fl;
  }
  __syncthreads();
  if (tid < NL) sk_ws[b*NL + tid] = ssk[tid];
  for (int t = tid; t < NT; t += 256) o_fm[b*NT + t] = (t < sfl) ? 1.f : 0.f;
}

// ------ K2: merged param prep: conv-fold E/bias2 + WoT/LwT bf16 packs ----------
__global__ __launch_bounds__(256) void k_setup(
    const float* __restrict__ Wp_w, const float* __restrict__ C_w, const float* __restrict__ bp_w,
    const float* __restrict__ Wp_c, const float* __restrict__ C_c, const float* __restrict__ bp_c,
    const float* __restrict__ Wo, const float* __restrict__ Lw,
    float* __restrict__ Ew, float* __restrict__ Ec,
    float* __restrict__ bw2, float* __restrict__ bc2,
    ushort_t* __restrict__ WoT, ushort_t* __restrict__ LwT)
{
  int bid = blockIdx.x;
  if (bid < 48){
    int gid = bid*256 + threadIdx.x;   // 12288 = 2 * 8*3*256
    int branch = gid / 6144;
    int r = gid % 6144;
    int d = r & 255;
    int ock = r >> 8;            // oc*3+k
    int oc = ock / 3, k = ock % 3;
    const float* Wp = branch ? Wp_c : Wp_w;
    const float* C  = branch ? C_c  : C_w;
    float acc = 0.f;
    for (int i = 0; i < ND; ++i) acc += C[(oc*ND + i)*3 + k] * Wp[i*ND + d];
    (branch ? Ec : Ew)[r] = acc;
    if (d == 0){
      const float* bp = branch ? bp_c : bp_w;
      float bb = 0.f;
      for (int i = 0; i < ND; ++i) bb += C[(oc*ND + i)*3 + k] * bp[i];
      (branch ? bc2 : bw2)[ock] = bb;
    }
  } else {
    int gid = (bid - 48)*256 + threadIdx.x;   // 393216
    if (gid < 131072){
      int n = gid >> 8, k = gid & 255;
      WoT[gid] = f2bf(Wo[(size_t)k*512 + n]);
    } else {
      int r = gid - 131072;        // q*65536 + n*256 + d
      int d = r & 255;
      int qn = r >> 8;
      int q = qn >> 8, n = qn & 255;
      LwT[r] = f2bf(Lw[((size_t)q*256 + d)*256 + n]);
    }
  }
}

// ------ K3: phoneme (b,d,l) -> phT fp32 (b,l,d) + phTb bf16 (b,l[256pad],d) ----
__global__ void k_transpose(const float* __restrict__ ph, float* __restrict__ phT,
                            ushort_t* __restrict__ phTb)
{
  __shared__ float tile[32][33];
  int b = blockIdx.z;
  int l0 = blockIdx.x*32, d0 = blockIdx.y*32;   // grid.x = 8 covers l 0..255
  int tx = threadIdx.x, ty = threadIdx.y;  // 32 x 8
  #pragma unroll
  for (int i = 0; i < 4; ++i){
    int d = d0 + ty + i*8, l = l0 + tx;
    tile[ty + i*8][tx] = (l < NL) ? ph[((size_t)b*ND + d)*NL + l] : 0.f;
  }
  __syncthreads();
  #pragma unroll
  for (int i = 0; i < 4; ++i){
    int l = l0 + ty + i*8, d = d0 + tx;
    float v = tile[tx][ty + i*8];
    if (l < NL) phT[((size_t)b*NL + l)*ND + d] = v;
    phTb[((size_t)b*256 + l)*ND + d] = f2bf(v);   // rows >=200 are zeros
  }
}

// ------ K4: fused conv-swish h + t-invariant MLP bases per (b,l) ---------------
__global__ __launch_bounds__(256) void k_hwc2(const float* __restrict__ phT,
    const float* __restrict__ dur, const float* __restrict__ sk_ws,
    const float* __restrict__ Ew, const float* __restrict__ Ec,
    const float* __restrict__ bw2, const float* __restrict__ bc2,
    const float* __restrict__ cbw, const float* __restrict__ cbc,
    const float* __restrict__ Mw, const float* __restrict__ mbw,
    const float* __restrict__ Mc, const float* __restrict__ mbc,
    float4* __restrict__ base)
{
  int b = blockIdx.y, x = blockIdx.x, tid = threadIdx.x;
  if (x >= 13){
    int l0 = 208 + (x - 13)*16;
    if (tid < 32)
      base[((size_t)(b*256 + l0 + (tid >> 1)))*2 + (tid & 1)] = make_float4(0,0,0,0);
    return;
  }
  __shared__ float sh[16][17];
  int lu = tid >> 4, u = tid & 15;
  int l = x*16 + lu;
  float h = 0.f;
  if (l < NL){
    int branch = u >> 3, oc = u & 7;
    const float* E  = branch ? Ec  : Ew;
    const float* b2 = branch ? bc2 : bw2;
    float val = (branch ? cbc : cbw)[oc];
    #pragma unroll
    for (int k = 0; k < 3; ++k){
      int ll = l + k - 1;
      if (ll < 0 || ll >= NL) continue;      // SAME zero-padding: drop term+bias
      float acc = b2[oc*3 + k];
      const float4* Er = (const float4*)(E + (oc*3 + k)*ND);
      const float4* pr = (const float4*)(phT + ((size_t)b*NL + ll)*ND);
      #pragma unroll 8
      for (int d = 0; d < 64; ++d){
        float4 e = Er[d], p = pr[d];
        acc += e.x*p.x + e.y*p.y + e.z*p.z + e.w*p.w;
      }
      val += acc;
    }
    float pm = (dur[b*NL + l] > 0.5f) ? 1.f : 0.f;
    h = silu_f(val) * pm;
  }
  sh[lu][u] = h;
  __syncthreads();
  if (tid < 16){
    int ll = x*16 + tid;
    float4 o0 = make_float4(0,0,0,0);
    float4 o1 = make_float4(0,0,0,0);
    if (ll < NL){
      float dl  = dur[b*NL + ll];
      float pm  = (dl > 0.5f) ? 1.f : 0.f;
      float skl = sk_ws[b*NL + ll];
      float c1[4], c2[2];
      #pragma unroll
      for (int q = 0; q < 4; ++q) c1[q] = mbw[q] + dl*Mw[4 + q] - skl*Mw[q];
      #pragma unroll
      for (int p = 0; p < 2; ++p) c2[p] = mbc[p] + dl*Mc[2 + p] - skl*Mc[p];
      #pragma unroll
      for (int j = 0; j < 8; ++j){
        float hwv = sh[tid][j], hcv = sh[tid][8 + j];
        #pragma unroll
        for (int q = 0; q < 4; ++q) c1[q] += hwv*Mw[(2 + j)*4 + q];
        #pragma unroll
        for (int p = 0; p < 2; ++p) c2[p] += hcv*Mc[(2 + j)*2 + p];
      }
      o0 = make_float4(c1[0], c1[1], c1[2], c1[3]);
      o1 = make_float4(c2[0], c2[1], pm, 0.f);
    }
    base[((size_t)(b*256 + ll))*2 + 0] = o0;
    base[((size_t)(b*256 + ll))*2 + 1] = o1;
  }
}

// ------- K5: MFMA Gt[b][n][q*200+l] = sum_d LwT[q][n][d] * phTb[b][l][d] -------
__global__ __launch_bounds__(256) void k_gemmG_mfma(
    const ushort_t* __restrict__ LwT,   // [4][256][256] bf16
    const ushort_t* __restrict__ phTb,  // [16][256][256] bf16
    ushort_t* __restrict__ Gt)          // [16][256][800] bf16
{
  __shared__ ushort_t As[4096];
  __shared__ ushort_t Bs[4096];
  int bq = blockIdx.z; int b = bq >> 2, q = bq & 3;
  int m0 = blockIdx.y * 128;            // n dim (256 -> 2 tiles)
  int n0 = blockIdx.x * 128;            // l dim (200 -> 2 tiles padded)
  int tid = threadIdx.x, lane = tid & 63, wave = tid >> 6;
  int wm = wave >> 1, wn = wave & 1;
  int col = lane & 15, kg4 = lane >> 4;

  f32x4 acc[4][4] = {};

  for (int kt = 0; kt < 8; ++kt){
    int k0 = kt*32;
    #pragma unroll
    for (int r = 0; r < 2; ++r){
      int o = wave*1024 + r*4096;
      int co = o + (lane << 4);
      int kg = co >> 11, row = (co >> 4) & 127;
      const ushort_t* ga = LwT + ((size_t)(q*256 + m0 + row))*256 + k0 + kg*8;
      __builtin_amdgcn_global_load_lds(GLB_AS(ga), LDS_AS(As + (o >> 1)), 16, 0, 0);
      const ushort_t* gb = phTb + ((size_t)(b*256 + n0 + row))*256 + k0 + kg*8;
      __builtin_amdgcn_global_load_lds(GLB_AS(gb), LDS_AS(Bs + (o >> 1)), 16, 0, 0);
    }
    __builtin_amdgcn_s_waitcnt(0);
    __syncthreads();
    const bf16x8* Av = (const bf16x8*)As;
    const bf16x8* Bv = (const bf16x8*)Bs;
    bf16x8 afr[4], bfr[4];
    #pragma unroll
    for (int i = 0; i < 4; ++i) afr[i] = Av[kg4*128 + wm*64 + i*16 + col];
    #pragma unroll
    for (int j = 0; j < 4; ++j) bfr[j] = Bv[kg4*128 + wn*64 + j*16 + col];
    #pragma unroll
    for (int i = 0; i < 4; ++i)
      #pragma unroll
      for (int j = 0; j < 4; ++j)
        acc[i][j] = __builtin_amdgcn_mfma_f32_16x16x32_bf16(afr[i], bfr[j], acc[i][j], 0, 0, 0);
    __syncthreads();
  }

  int rq = lane >> 4;
  #pragma unroll
  for (int i = 0; i < 4; ++i){
    #pragma unroll
    for (int r = 0; r < 4; ++r){
      int n = m0 + wm*64 + i*16 + rq*4 + r;
      #pragma unroll
      for (int j = 0; j < 4; ++j){
        int l = n0 + wn*64 + j*16 + col;
        if (l < NL)
          Gt[((size_t)b*ND + n)*800 + q*NL + l] = f2bf(acc[i][j][r]);
      }
    }
  }
}

// ------- K6: FUSED softmax + vh GEMM per (b, 32-t tile) ------------------------
// Phase 1: each wave computes softmax for 8 t's -> w into LDS A-tile (bf16,
//          row stride 808 for bank spread), wout (fp32 out), wc8 into LDS.
// Phase 2: vh = A(32x800) @ Gt^T(256x800), Gt streamed via global_load_lds.
// Epilogue: whc = fm * (vh + lbw + (lbc + wc8.Lc)) -> bf16.
#define AP 808
__global__ __launch_bounds__(256) void k_wv_fused(
    const float4* __restrict__ base,
    const int* __restrict__ fl_ws,
    const float* __restrict__ Mw, const float* __restrict__ Mc,
    const ushort_t* __restrict__ Gt,    // [16][256][800] bf16
    const float* __restrict__ Lc,       // [8][256]
    const float* __restrict__ lbc,      // [256]
    const float* __restrict__ lbw,      // [256]
    float* __restrict__ wout,
    ushort_t* __restrict__ whc)         // [16000][256] bf16
{
  __shared__ ushort_t As[32*AP];   // 50.5 KB w-tile [t_local][k=q*200+l]
  __shared__ ushort_t Bs[8192];    // 16 KB  [kg(4)][n(256)][8]
  __shared__ float    wcs[32][8];  // 1 KB per-t wc
  int b = blockIdx.y;
  int m0 = blockIdx.x * 32;        // t tile (32 tiles cover 0..1023)
  int tid = threadIdx.x, lane = tid & 63, wave = tid >> 6;
  int col = lane & 15, kg4 = lane >> 4;
  int fl = fl_ws[b];

  // ---------------- phase 1: softmax for 8 t's per wave ----------------
  for (int s = 0; s < 8; ++s){
    int tl = wave*8 + s;
    int t = m0 + tl;
    if (t >= fl){                       // masked or beyond NT
      for (int k = lane; k < 800; k += 64) As[tl*AP + k] = 0;
      if (lane < 8) wcs[tl][lane] = 0.f;
      if (t < NT){
        #pragma unroll
        for (int q = 0; q < 4; ++q)
          #pragma unroll
          for (int c = 0; c < 4; ++c){
            int l = c*64 + lane;
            if (l < NL) wout[(((size_t)(b*4 + q))*NT + t)*NL + l] = 0.f;
          }
      }
      continue;
    }
    float t1 = (float)(t + 1);
    float tqw[4], tqc[2];
    #pragma unroll
    for (int q = 0; q < 4; ++q) tqw[q] = t1 * Mw[q];
    #pragma unroll
    for (int p = 0; p < 2; ++p) tqc[p] = t1 * Mc[p];
    float z[4][4], cv[4][2], msk[4];
    float m[4] = {-INFINITY, -INFINITY, -INFINITY, -INFINITY};
    #pragma unroll
    for (int c = 0; c < 4; ++c){
      int l = c*64 + lane;
      float4 b0 = base[((size_t)(b*256 + l))*2 + 0];
      float4 b1 = base[((size_t)(b*256 + l))*2 + 1];
      float pm = b1.z;
      msk[c] = pm;
      float zz[4] = { b0.x + tqw[0], b0.y + tqw[1], b0.z + tqw[2], b0.w + tqw[3] };
      #pragma unroll
      for (int q = 0; q < 4; ++q){
        float sv = silu_f(zz[q]);
        z[c][q] = (pm > 0.f) ? sv : -INFINITY;
        m[q] = fmaxf(m[q], z[c][q]);
      }
      cv[c][0] = silu_f(b1.x + tqc[0]);
      cv[c][1] = silu_f(b1.y + tqc[1]);
    }
    #pragma unroll
    for (int q = 0; q < 4; ++q){
      float v = m[q];
      #pragma unroll
      for (int off = 32; off; off >>= 1) v = fmaxf(v, __shfl_xor(v, off));
      m[q] = v;
    }
    float s4[4] = {0,0,0,0};
    #pragma unroll
    for (int c = 0; c < 4; ++c){
      #pragma unroll
      for (int q = 0; q < 4; ++q){
        float e = (msk[c] > 0.f) ? __expf(z[c][q] - m[q]) : 0.f;
        z[c][q] = e;
        s4[q] += e;
      }
    }
    #pragma unroll
    for (int q = 0; q < 4; ++q){
      float v = s4[q];
      #pragma unroll
      for (int off = 32; off; off >>= 1) v += __shfl_xor(v, off);
      s4[q] = 1.f / v;
    }
    float wc[8] = {0,0,0,0,0,0,0,0};
    #pragma unroll
    for (int c = 0; c < 4; ++c){
      int l = c*64 + lane;
      bool lv = l < NL;
      #pragma unroll
      for (int q = 0; q < 4; ++q){
        float wq = z[c][q] * s4[q];
        if (lv){
          wout[(((size_t)(b*4 + q))*NT + t)*NL + l] = wq;
          As[tl*AP + q*NL + l] = f2bf(wq);
        }
        wc[q*2 + 0] += wq * cv[c][0];
        wc[q*2 + 1] += wq * cv[c][1];
      }
    }
    #pragma unroll
    for (int u = 0; u < 8; ++u){
      float v = wc[u];
      #pragma unroll
      for (int off = 32; off; off >>= 1) v += __shfl_xor(v, off);
      wc[u] = v;
    }
    if (lane == 0){
      #pragma unroll
      for (int u = 0; u < 8; ++u) wcs[tl][u] = wc[u];
    }
  }
  __syncthreads();

  // ---------------- phase 2: MFMA over K=800 ----------------
  f32x4 acc[2][4] = {};
  for (int kt = 0; kt < 25; ++kt){
    int k0 = kt*32;
    #pragma unroll
    for (int r = 0; r < 4; ++r){
      int o = (wave*4 + r) << 10;          // 16 x 1KB chunks = 16 KB
      int co = o + (lane << 4);
      int kg = co >> 12, row = (co >> 4) & 255;
      const ushort_t* gb = Gt + ((size_t)(b*ND + row))*800 + k0 + kg*8;
      __builtin_amdgcn_global_load_lds(GLB_AS(gb), LDS_AS(Bs + (co >> 1)), 16, 0, 0);
    }
    __builtin_amdgcn_s_waitcnt(0);
    __syncthreads();
    const bf16x8* Bv = (const bf16x8*)Bs;
    bf16x8 afr[2], bfr[4];
    #pragma unroll
    for (int i = 0; i < 2; ++i)
      afr[i] = *(const bf16x8*)(&As[(i*16 + col)*AP + k0 + kg4*8]);
    #pragma unroll
    for (int j = 0; j < 4; ++j) bfr[j] = Bv[kg4*256 + wave*64 + j*16 + col];
    #pragma unroll
    for (int i = 0; i < 2; ++i)
      #pragma unroll
      for (int j = 0; j < 4; ++j)
        acc[i][j] = __builtin_amdgcn_mfma_f32_16x16x32_bf16(afr[i], bfr[j], acc[i][j], 0, 0, 0);
    __syncthreads();
  }

  // ---------------- epilogue: whc = fm*(vh + lbw + vc) ----------------
  int rq = lane >> 4;
  float lcn[4][8], lbn[4], lbwn[4];
  #pragma unroll
  for (int j = 0; j < 4; ++j){
    int n = wave*64 + j*16 + col;
    lbn[j] = lbc[n]; lbwn[j] = lbw[n];
    #pragma unroll
    for (int u = 0; u < 8; ++u) lcn[j][u] = Lc[u*ND + n];
  }
  #pragma unroll
  for (int i = 0; i < 2; ++i){
    #pragma unroll
    for (int r = 0; r < 4; ++r){
      int tl = i*16 + rq*4 + r;
      int t = m0 + tl;
      if (t >= NT) continue;
      float f = (t < fl) ? 1.f : 0.f;
      #pragma unroll
      for (int j = 0; j < 4; ++j){
        float vcv = lbn[j]
          + wcs[tl][0]*lcn[j][0] + wcs[tl][1]*lcn[j][1]
          + wcs[tl][2]*lcn[j][2] + wcs[tl][3]*lcn[j][3]
          + wcs[tl][4]*lcn[j][4] + wcs[tl][5]*lcn[j][5]
          + wcs[tl][6]*lcn[j][6] + wcs[tl][7]*lcn[j][7];
        int n = wave*64 + j*16 + col;
        whc[((size_t)b*NT + t)*ND + n] = f2bf(f * (acc[i][j][r] + lbwn[j] + vcv));
      }
    }
  }
}

// ------- K7: MFMA out = WoT(s-rows) x whc(bt-rows): coalesced t-stores ---------
__global__ __launch_bounds__(256) void k_gemmO_mfma(
    const ushort_t* __restrict__ whc,   // [16000][256] bf16
    const ushort_t* __restrict__ WoT,   // [512][256] bf16
    const float* __restrict__ bo,       // [512]
    float* __restrict__ o_mean, float* __restrict__ o_lstd)
{
  __shared__ ushort_t As[4096];
  __shared__ ushort_t Bs[4096];
  int m0 = blockIdx.y * 128;            // s (4 tiles over 512)
  int n0 = blockIdx.x * 128;            // bt (125 tiles over 16000)
  int tid = threadIdx.x, lane = tid & 63, wave = tid >> 6;
  int wm = wave >> 1, wn = wave & 1;
  int col = lane & 15, kg4 = lane >> 4;

  f32x4 acc[4][4] = {};

  for (int kt = 0; kt < 8; ++kt){
    int k0 = kt*32;
    #pragma unroll
    for (int r = 0; r < 2; ++r){
      int o = wave*1024 + r*4096;
      int co = o + (lane << 4);
      int kg = co >> 11, row = (co >> 4) & 127;
      const ushort_t* ga = WoT + ((size_t)(m0 + row))*ND + k0 + kg*8;
      __builtin_amdgcn_global_load_lds(GLB_AS(ga), LDS_AS(As + (o >> 1)), 16, 0, 0);
      const ushort_t* gb = whc + ((size_t)(n0 + row))*ND + k0 + kg*8;
      __builtin_amdgcn_global_load_lds(GLB_AS(gb), LDS_AS(Bs + (o >> 1)), 16, 0, 0);
    }
    __builtin_amdgcn_s_waitcnt(0);
    __syncthreads();
    const bf16x8* Av = (const bf16x8*)As;
    const bf16x8* Bv = (const bf16x8*)Bs;
    bf16x8 afr[4], bfr[4];
    #pragma unroll
    for (int i = 0; i < 4; ++i) afr[i] = Av[kg4*128 + wm*64 + i*16 + col];
    #pragma unroll
    for (int j = 0; j < 4; ++j) bfr[j] = Bv[kg4*128 + wn*64 + j*16 + col];
    #pragma unroll
    for (int i = 0; i < 4; ++i)
      #pragma unroll
      for (int j = 0; j < 4; ++j)
        acc[i][j] = __builtin_amdgcn_mfma_f32_16x16x32_bf16(afr[i], bfr[j], acc[i][j], 0, 0, 0);
    __syncthreads();
  }

  int rq = lane >> 4;
  #pragma unroll
  for (int i = 0; i < 4; ++i){
    #pragma unroll
    for (int r = 0; r < 4; ++r){
      int s = m0 + wm*64 + i*16 + rq*4 + r;
      float bov = bo[s];
      #pragma unroll
      for (int j = 0; j < 4; ++j){
        int bt = n0 + wn*64 + j*16 + col;
        int b = bt / NT, t = bt - b*NT;
        float v = acc[i][j][r] + bov;
        if (s < ND) o_mean[((size_t)b*ND + s)*NT + t] = v;
        else        o_lstd[((size_t)b*ND + (s - ND))*NT + t] = v;
      }
    }
  }
}

extern "C" void kernel_launch(void* const* d_in, const int* in_sizes, int n_in,
                              void* d_out, int out_size, void* d_ws, size_t ws_size,
                              hipStream_t stream)
{
  const float* dur = (const float*)d_in[0];
  const float* ph  = (const float*)d_in[1];
  // d_in[2] phoneme_mask: unused (pm == durations > 0)
  const float* Wpw = (const float*)d_in[3];
  const float* bpw = (const float*)d_in[4];
  const float* Cw  = (const float*)d_in[5];
  const float* cbw = (const float*)d_in[6];
  const float* Mw  = (const float*)d_in[7];
  const float* mbw = (const float*)d_in[8];
  const float* Lw  = (const float*)d_in[9];
  const float* lbw = (const float*)d_in[10];
  const float* Wpc = (const float*)d_in[11];
  const float* bpc = (const float*)d_in[12];
  const float* Cc  = (const float*)d_in[13];
  const float* cbc = (const float*)d_in[14];
  const float* Mc  = (const float*)d_in[15];
  const float* mbc = (const float*)d_in[16];
  const float* Lc  = (const float*)d_in[17];
  const float* lbc = (const float*)d_in[18];
  const float* Wo  = (const float*)d_in[19];
  const float* bo  = (const float*)d_in[20];

  float* out    = (float*)d_out;
  float* o_mean = out;
  float* o_lstd = out + (size_t)NB*ND*NT;
  float* o_fm   = o_lstd + (size_t)NB*ND*NT;
  float* o_fl   = o_fm + NB*NT;
  float* o_w    = o_fl + NB;

  float* ws   = (float*)d_ws;
  float* phT  = ws + OFF_PHT;
  float* sk   = ws + OFF_SK;
  float* Ew   = ws + OFF_EW;
  float* Ec   = ws + OFF_EC;
  float* bw2  = ws + OFF_BW2;
  float* bc2  = ws + OFF_BC2;
  int*   fl   = (int*)(ws + OFF_FL);
  ushort_t* Gt   = (ushort_t*)(ws + OFF_GT);
  ushort_t* whc  = (ushort_t*)(ws + OFF_WHC);
  ushort_t* WoT  = (ushort_t*)(ws + OFF_WOT);
  float4*   base = (float4*)(ws + OFF_BASE);
  ushort_t* phTb = (ushort_t*)(ws + OFF_PHTB);
  ushort_t* LwT  = (ushort_t*)(ws + OFF_LWT);

  k_prep<<<NB, 256, 0, stream>>>(dur, sk, fl, o_fm, o_fl);
  k_setup<<<1584, 256, 0, stream>>>(Wpw, Cw, bpw, Wpc, Cc, bpc, Wo, Lw,
                                    Ew, Ec, bw2, bc2, WoT, LwT);
  {
    dim3 g(8, 8, NB), blk(32, 8);
    k_transpose<<<g, blk, 0, stream>>>(ph, phT, phTb);
  }
  {
    dim3 g(16, NB);
    k_hwc2<<<g, 256, 0, stream>>>(phT, dur, sk, Ew, Ec, bw2, bc2, cbw, cbc,
                                  Mw, mbw, Mc, mbc, base);
  }
  {
    dim3 g(2, 2, NB*4);
    k_gemmG_mfma<<<g, 256, 0, stream>>>(LwT, phTb, Gt);
  }
  {
    dim3 g(32, NB);
    k_wv_fused<<<g, 256, 0, stream>>>(base, fl, Mw, Mc, Gt, Lc, lbc, lbw,
                                      o_w, whc);
  }
  {
    dim3 g(125, 4);
    k_gemmO_mfma<<<g, 256, 0, stream>>>(whc, WoT, bo, o_mean, o_lstd);
  }
}